// Round 15
// baseline (217.053 us; speedup 1.0000x reference)
//
#include <hip/hip_runtime.h>
#include <hip/hip_bf16.h>
#include <stdint.h>

typedef unsigned short u16;
typedef __attribute__((ext_vector_type(8))) short bf16x8;   // 8 bf16 = 4 VGPRs
typedef __attribute__((ext_vector_type(4))) float f32x4;

#define DEV __device__ __forceinline__

DEV u16 f2bf(float f) {
  union { float f; unsigned u; } v; v.f = f;
  unsigned r = (v.u + 0x7fffu + ((v.u >> 16) & 1u)) >> 16;   // RNE
  return (u16)r;
}

// packed 2x f32 -> 2x bf16 (v_cvt_pk_bf16_f32), RNE
DEV unsigned pk2(float lo, float hi) {
  union { __hip_bfloat162 h; unsigned u; } c;
  c.h = __float22bfloat162_rn(make_float2(lo, hi));
  return c.u;
}

DEV f32x4 mfma16(bf16x8 a, bf16x8 b, f32x4 c) {
  return __builtin_amdgcn_mfma_f32_16x16x32_bf16(a, b, c, 0, 0, 0);
}

DEV void gload_lds16(const u16* g, u16* l) {
  __builtin_amdgcn_global_load_lds((const __attribute__((address_space(1))) void*)g,
                                   (__attribute__((address_space(3))) void*)l, 16, 0, 0);
}

// softmax logit pre-scale folded into Q: dh^-0.5 (=1/8) * log2(e), so exp = exp2
#define QSCALE 0.18033688011112042f

// ---------------- fused fp32 -> bf16 convert (+ optional row-major copy) + transpose ----------------
__global__ void cvt_xpose_kernel(const float* __restrict__ src, u16* __restrict__ dst_rm,
                                 u16* __restrict__ dst_tp, int R, int C,
                                 long zS, long zRM, long zTP) {
  __shared__ u16 tile[64][72];
  src += (size_t)blockIdx.z * zS;
  dst_tp += (size_t)blockIdx.z * zTP;
  int r0 = blockIdx.y * 64, c0 = blockIdx.x * 64;
  int tr = threadIdx.x >> 2, tc = (threadIdx.x & 3) * 16;
  const float* s = src + (size_t)(r0 + tr) * C + c0 + tc;
  u16 loc[16];
#pragma unroll
  for (int q = 0; q < 4; ++q) {
    float4 v = ((const float4*)s)[q];
    loc[q * 4 + 0] = f2bf(v.x); loc[q * 4 + 1] = f2bf(v.y);
    loc[q * 4 + 2] = f2bf(v.z); loc[q * 4 + 3] = f2bf(v.w);
  }
#pragma unroll
  for (int i = 0; i < 16; ++i) tile[tr][tc + i] = loc[i];
  if (dst_rm) {
    u16* d = dst_rm + (size_t)blockIdx.z * zRM + (size_t)(r0 + tr) * C + c0 + tc;
    *(bf16x8*)d = *(const bf16x8*)&loc[0];
    *(bf16x8*)(d + 8) = *(const bf16x8*)&loc[8];
  }
  __syncthreads();
  u16 tmp[16];
#pragma unroll
  for (int i = 0; i < 16; ++i) tmp[i] = tile[tc + i][tr];
  u16* d = dst_tp + (size_t)(c0 + tr) * R + r0 + tc;
  *(bf16x8*)d = *(const bf16x8*)&tmp[0];
  *(bf16x8*)(d + 8) = *(const bf16x8*)&tmp[8];
}

// ---------------- merged: 4 weight converts (y 0-3) + proj_k/proj_v transposes (y 4-5) ----------------
__global__ void cvt_misc_kernel(const float* __restrict__ s0, const float* __restrict__ s1,
                                const float* __restrict__ s2, const float* __restrict__ s3,
                                u16* __restrict__ d0, u16* __restrict__ d1,
                                u16* __restrict__ d2, u16* __restrict__ d3,
                                const float* __restrict__ pk, const float* __restrict__ pv,
                                u16* __restrict__ projT) {
  __shared__ u16 tile[64][72];
  const int y = blockIdx.y;
  if (y < 4) {
    const float* s; u16* d;
    switch (y) {
      case 0: s = s0; d = d0; break;
      case 1: s = s1; d = d1; break;
      case 2: s = s2; d = d2; break;
      default: s = s3; d = d3; break;
    }
    int i = blockIdx.x * 256 + threadIdx.x;
    float4 v = ((const float4*)s)[i];
    ushort4 o; o.x = f2bf(v.x); o.y = f2bf(v.y); o.z = f2bf(v.z); o.w = f2bf(v.w);
    ((ushort4*)d)[i] = o;
    return;
  }
  if (blockIdx.x >= 256) return;
  const float* src = (y == 4) ? pk : pv;
  u16* dst = projT + (size_t)(y - 4) * 1048576;
  int r0 = (blockIdx.x >> 2) * 64, c0 = (blockIdx.x & 3) * 64;
  int tr = threadIdx.x >> 2, tc = (threadIdx.x & 3) * 16;
  const float* s = src + (size_t)(r0 + tr) * 256 + c0 + tc;
  u16 loc[16];
#pragma unroll
  for (int q = 0; q < 4; ++q) {
    float4 v = ((const float4*)s)[q];
    loc[q * 4 + 0] = f2bf(v.x); loc[q * 4 + 1] = f2bf(v.y);
    loc[q * 4 + 2] = f2bf(v.z); loc[q * 4 + 3] = f2bf(v.w);
  }
#pragma unroll
  for (int i = 0; i < 16; ++i) tile[tr][tc + i] = loc[i];
  __syncthreads();
  u16 tmp[16];
#pragma unroll
  for (int i = 0; i < 16; ++i) tmp[i] = tile[tc + i][tr];
  u16* d = dst + (size_t)(c0 + tr) * 4096 + r0 + tc;
  *(bf16x8*)d = *(const bf16x8*)&tmp[0];
  *(bf16x8*)(d + 8) = *(const bf16x8*)&tmp[8];
}

// ---------------- split-K reduce ----------------
__global__ void reduce4_kernel(const float* __restrict__ part, u16* __restrict__ out) {
  int i = blockIdx.x * 256 + threadIdx.x;
  const float4* p = (const float4*)part;
  float4 a = p[i], b = p[i + 524288], c = p[i + 1048576], d = p[i + 1572864];
  ushort4 o;
  o.x = f2bf(a.x + b.x + c.x + d.x);
  o.y = f2bf(a.y + b.y + c.y + d.y);
  o.z = f2bf(a.z + b.z + c.z + d.z);
  o.w = f2bf(a.w + b.w + c.w + d.w);
  ((ushort4*)out)[i] = o;
}

// ------------- 128x128 2-phase GEMM (xp split-K and kv) -------------
template<int OMODE>
__global__ __launch_bounds__(256, 4)
void gemm_bt_kernel(const u16* __restrict__ A, const u16* __restrict__ Bt,
                    const u16* __restrict__ Bt2, void* __restrict__ Cout,
                    u16* __restrict__ CoutT, const float* __restrict__ bias, float cscale,
                    int ldA, int ldB, int ldC, int Klen,
                    long zA, long zB, long zC, int bMod, long kChunkA, long kChunkB) {
  __shared__ __align__(16) u16 smA[2][128 * 32];
  __shared__ __align__(16) u16 smB[2][128 * 32];
  const int t = threadIdx.x;
  const int lane = t & 63, wave = t >> 6;
  const int wm = wave & 1, wn = wave >> 1;
  const int g = lane >> 4, r = lane & 15;
  const int id = blockIdx.y * gridDim.x + blockIdx.x;
  const int cpx = (gridDim.x * gridDim.y) >> 3;
  const int s = (id & 7) * cpx + (id >> 3);
  const int bx = s % gridDim.x, by = s / gridDim.x;
  const int z = blockIdx.z;
  const int b = z % bMod, kc = z / bMod;
  const u16* Ab = A + (size_t)b * zA + (size_t)kc * kChunkA;
  const u16* Bbase = (Bt2 && (b & 1)) ? Bt2 : Bt;
  const u16* Bb = Bbase + (size_t)b * zB + (size_t)kc * kChunkB;
  const int m0 = by * 128, n0 = bx * 128;
  const int srow = t >> 2;
  const int lslot = ((t & 3) + 4 - ((srow >> 1) & 3)) & 3;

  f32x4 acc[4][4];
#pragma unroll
  for (int m = 0; m < 4; ++m)
#pragma unroll
    for (int n = 0; n < 4; ++n) acc[m][n] = f32x4{0.f, 0.f, 0.f, 0.f};

  auto STAGE = [&](int buf, int k0) {
#pragma unroll
    for (int p = 0; p < 2; ++p) {
      int row = p * 64 + srow;
      gload_lds16(Ab + (size_t)(m0 + row) * ldA + k0 + lslot * 8, &smA[buf][p * 2048 + wave * 512]);
      gload_lds16(Bb + (size_t)(n0 + row) * ldB + k0 + lslot * 8, &smB[buf][p * 2048 + wave * 512]);
    }
  };

  const int nt = Klen >> 5;
  STAGE(0, 0);
  __syncthreads();
  int cur = 0;
  for (int it = 0; it < nt; ++it) {
    if (it + 1 < nt) STAGE(cur ^ 1, (it + 1) << 5);
    bf16x8 af[4], bfr[4];
#pragma unroll
    for (int m = 0; m < 4; ++m) {
      int row = wm * 64 + m * 16 + r;
      int ps = (g + (row >> 1)) & 3;
      af[m] = *(const bf16x8*)&smA[cur][row * 32 + ps * 8];
    }
#pragma unroll
    for (int n = 0; n < 4; ++n) {
      int row = wn * 64 + n * 16 + r;
      int ps = (g + (row >> 1)) & 3;
      bfr[n] = *(const bf16x8*)&smB[cur][row * 32 + ps * 8];
    }
#pragma unroll
    for (int m = 0; m < 4; ++m)
#pragma unroll
      for (int n = 0; n < 4; ++n)
        acc[m][n] = mfma16(af[m], bfr[n], acc[m][n]);
    __syncthreads();
    cur ^= 1;
  }

  if constexpr (OMODE == 0) {
    u16* C = (u16*)Cout + (size_t)z * zC;
#pragma unroll
    for (int n = 0; n < 4; ++n) {
      int col = n0 + wn * 64 + n * 16 + r;
#pragma unroll
      for (int m = 0; m < 4; ++m) {
        int rowb = m0 + wm * 64 + m * 16 + 4 * g;
#pragma unroll
        for (int rr = 0; rr < 4; ++rr)
          C[(size_t)(rowb + rr) * ldC + col] = f2bf(acc[m][n][rr] * cscale);
      }
    }
  } else if constexpr (OMODE == 2) {
    float* myF = ((float*)(wave < 2 ? (void*)&smA[0][0] : (void*)&smB[0][0])) + (wave & 1) * 2048;
    float* Cg = (float*)Cout + (size_t)z * zC + (size_t)(m0 + wm * 64) * ldC + n0 + wn * 64;
#pragma unroll
    for (int np = 0; np < 2; ++np) {
#pragma unroll
      for (int n2 = 0; n2 < 2; ++n2)
#pragma unroll
        for (int m = 0; m < 4; ++m)
#pragma unroll
          for (int rr = 0; rr < 4; ++rr) {
            int rl = m * 16 + 4 * g + rr;
            int cl = n2 * 16 + r;
            myF[rl * 32 + ((((cl >> 2) ^ (rl & 7)) & 7) << 2) + (cl & 3)] =
                acc[m][np * 2 + n2][rr];
          }
      __syncthreads();
#pragma unroll
      for (int i = 0; i < 8; ++i) {
        int idx = i * 64 + lane;
        int row = idx >> 3, c = idx & 7;
        float4 v = *(const float4*)&myF[row * 32 + (((c ^ (row & 7)) & 7) << 2)];
        *(float4*)&Cg[(size_t)row * ldC + np * 32 + c * 4] = v;
      }
      __syncthreads();
    }
  } else if constexpr (OMODE == 3) {
    if ((z & 1) == 0) {
      u16* C = (u16*)Cout + (size_t)(z >> 1) * zC;
#pragma unroll
      for (int n = 0; n < 4; ++n) {
        int col = n0 + wn * 64 + n * 16 + r;
#pragma unroll
        for (int m = 0; m < 4; ++m) {
          int rowb = m0 + wm * 64 + m * 16 + 4 * g;
#pragma unroll
          for (int rr = 0; rr < 4; ++rr)
            C[(size_t)(rowb + rr) * ldC + col] = f2bf(acc[m][n][rr]);
        }
      }
    } else {
      u16* C = CoutT + (size_t)(z >> 1) * zC;
#pragma unroll
      for (int n = 0; n < 4; ++n) {
        int col = n0 + wn * 64 + n * 16 + r;
#pragma unroll
        for (int m = 0; m < 4; ++m) {
          int rowb = m0 + wm * 64 + m * 16 + 4 * g;
          ushort4 o;
          o.x = f2bf(acc[m][n][0]); o.y = f2bf(acc[m][n][1]);
          o.z = f2bf(acc[m][n][2]); o.w = f2bf(acc[m][n][3]);
          *(ushort4*)&C[(size_t)col * 256 + rowb] = o;
        }
      }
    }
  } else {
    float* C = (float*)Cout + (size_t)z * zC;
#pragma unroll
    for (int n = 0; n < 4; ++n) {
      int col = n0 + wn * 64 + n * 16 + r;
      float bv = (OMODE == 1) ? bias[col] : 0.f;
#pragma unroll
      for (int m = 0; m < 4; ++m) {
        int rowb = m0 + wm * 64 + m * 16 + 4 * g;
#pragma unroll
        for (int rr = 0; rr < 4; ++rr)
          C[(size_t)(rowb + rr) * ldC + col] = acc[m][n][rr] + bv;
      }
    }
  }
}

// ------------- 256x128 GEMM, per-wave 128x64 (LDS-intensity 42.7 FLOP/B), 2 WGs/CU -------------
// 256 thr = 4 waves (2M x 2N); acc[8][4] = 128 AGPR. LDS 72 KB: A ring 3x16KB @0,
// B ring 3x8KB @49152B. 3-deep counted-vmcnt pipeline (6 gloads/stage -> vmcnt(6)).
// Rationale: 64x64-wave frag reads cap MfmaUtil at ~31% (8KB LDS / 262KFLOP = 32.8
// FLOP/B vs 128B/cyc LDS peak) — measured exactly. 128x64 wave raises intensity to
// 42.7 FLOP/B (+33% ceiling) while keeping 2 independent WGs/CU (2 waves/SIMD).
template<int OMODE>   // 0 = bf16*cscale, 1 = fp32 + bias
__global__ __launch_bounds__(256, 2)
void qgemm_kernel(const u16* __restrict__ A, const u16* __restrict__ Bt,
                  void* __restrict__ Cout, const float* __restrict__ bias,
                  float cscale, int ldA, int ldB, int ldC, int Klen) {
  __shared__ __align__(16) u16 lds[36864];   // 72 KB
  const int t = threadIdx.x;
  const int lane = t & 63, wave = t >> 6;
  const int g = lane >> 4, r = lane & 15;
  const int wm = wave >> 1, wn = wave & 1;           // 2M x 2N
  const int id = blockIdx.y * gridDim.x + blockIdx.x;  // gx=8, gy=64 -> 512 WGs
  const int cpx = (gridDim.x * gridDim.y) >> 3;
  const int s = (id & 7) * cpx + (id >> 3);
  const int bx = s & 7, by = s >> 3;
  const int m0 = by * 256, n0 = bx * 128;

  auto STAGE = [&](int buf, int k0) {
#pragma unroll
    for (int j = 0; j < 4; ++j) {                    // A: 256 rows x 4 slots
      int u = j * 256 + t;
      int row = u >> 2, psl = u & 3;
      int sl = (psl + 4 - ((row >> 1) & 3)) & 3;     // inverse swizzle on global source
      gload_lds16(A + (size_t)(m0 + row) * ldA + k0 + sl * 8,
                  lds + buf * 8192 + u * 8);
    }
#pragma unroll
    for (int j = 0; j < 2; ++j) {                    // B: 128 rows x 4 slots
      int u = j * 256 + t;
      int row = u >> 2, psl = u & 3;
      int sl = (psl + 4 - ((row >> 1) & 3)) & 3;
      gload_lds16(Bt + (size_t)(n0 + row) * ldB + k0 + sl * 8,
                  lds + 24576 + buf * 4096 + u * 8);
    }
  };

  f32x4 acc[8][4];
#pragma unroll
  for (int m = 0; m < 8; ++m)
#pragma unroll
    for (int n = 0; n < 4; ++n) acc[m][n] = f32x4{0.f, 0.f, 0.f, 0.f};

  const int nt = Klen >> 5;   // 32
  STAGE(0, 0);
  STAGE(1, 32);
  asm volatile("s_waitcnt vmcnt(6)" ::: "memory");   // tile 0 landed; tile 1 in flight
  __builtin_amdgcn_s_barrier();

  int cur = 0;
  for (int it = 0; it < nt; ++it) {
    int pre = cur + 2; if (pre >= 3) pre -= 3;
    if (it + 2 < nt) STAGE(pre, (it + 2) << 5);
    const u16* Ab = lds + cur * 8192;
    const u16* Bb = lds + 24576 + cur * 4096;
    bf16x8 af[8], bfr[4];
#pragma unroll
    for (int m = 0; m < 8; ++m) {
      int row = wm * 128 + m * 16 + r;               // 0..255
      int ps = (g + (row >> 1)) & 3;
      af[m] = *(const bf16x8*)&Ab[row * 32 + ps * 8];
    }
#pragma unroll
    for (int n = 0; n < 4; ++n) {
      int row = wn * 64 + n * 16 + r;                // 0..127
      int ps = (g + (row >> 1)) & 3;
      bfr[n] = *(const bf16x8*)&Bb[row * 32 + ps * 8];
    }
    __builtin_amdgcn_s_setprio(1);
#pragma unroll
    for (int m = 0; m < 8; ++m)
#pragma unroll
      for (int n = 0; n < 4; ++n)
        acc[m][n] = mfma16(af[m], bfr[n], acc[m][n]);
    __builtin_amdgcn_s_setprio(0);
    if (it + 1 < nt) {
      if (it + 2 < nt) asm volatile("s_waitcnt vmcnt(6)" ::: "memory");
      else             asm volatile("s_waitcnt vmcnt(0)" ::: "memory");
      __builtin_amdgcn_s_barrier();
    }
    cur = cur + 1; if (cur >= 3) cur -= 3;
  }
  __builtin_amdgcn_s_barrier();   // all LDS reads done before epilogue overwrites

  // epilogue: per-wave 128x64 tile; C row = m0+wm*128+m*16+4g+rr, col = n0+wn*64+n*16+r
  if constexpr (OMODE == 0) {
    u16* myT = lds + wave * 8192;   // 16 KB/wave x 4 = 64 KB
#pragma unroll
    for (int m = 0; m < 8; ++m)
#pragma unroll
      for (int n = 0; n < 4; ++n)
#pragma unroll
        for (int rr = 0; rr < 4; ++rr) {
          int rl = m * 16 + 4 * g + rr;
          int cl = n * 16 + r;
          myT[rl * 64 + (((cl >> 3) ^ (rl & 7)) << 3) + (cl & 7)] = f2bf(acc[m][n][rr] * cscale);
        }
    u16* Cg = (u16*)Cout + (size_t)(m0 + wm * 128) * ldC + n0 + wn * 64;
#pragma unroll
    for (int i = 0; i < 16; ++i) {
      int idx = i * 64 + lane;
      int row = idx >> 3, c8 = idx & 7;
      bf16x8 v = *(const bf16x8*)&myT[row * 64 + ((c8 ^ (row & 7)) << 3)];
      *(bf16x8*)&Cg[(size_t)row * ldC + c8 * 8] = v;
    }
  } else {
    float* myF = (float*)lds + wave * 4096;   // 16 KB/wave
    float bvn[4];
#pragma unroll
    for (int n = 0; n < 4; ++n) bvn[n] = bias[n0 + wn * 64 + n * 16 + r];
    float* Cg = (float*)Cout + (size_t)(m0 + wm * 128) * ldC + n0 + wn * 64;
#pragma unroll
    for (int half = 0; half < 2; ++half) {
#pragma unroll
      for (int m2 = 0; m2 < 4; ++m2)
#pragma unroll
        for (int n = 0; n < 4; ++n)
#pragma unroll
          for (int rr = 0; rr < 4; ++rr) {
            int rl = m2 * 16 + 4 * g + rr;
            int cl = n * 16 + r;
            myF[rl * 64 + (((cl >> 2) ^ (rl & 15)) << 2) + (cl & 3)] =
                acc[half * 4 + m2][n][rr] + bvn[n];
          }
#pragma unroll
      for (int i = 0; i < 16; ++i) {
        int idx = i * 64 + lane;
        int row = idx >> 4, c4 = idx & 15;
        float4 v = *(const float4*)&myF[row * 64 + ((c4 ^ (row & 15)) << 2)];
        *(float4*)&Cg[(size_t)(half * 64 + row) * ldC + c4 * 4] = v;
      }
    }
  }
}

// ------------- fused attention (frozen from R14) -------------
__global__ __launch_bounds__(256, 3)
void attn_kernel(const u16* __restrict__ Q, const u16* __restrict__ Kl,
                 const u16* __restrict__ VT, u16* __restrict__ Out) {
  __shared__ __align__(16) u16 sm[24576];   // 48 KB
  const int t = threadIdx.x, lane = t & 63, w = t >> 6;
  const int g = lane >> 4, r = lane & 15;
  const int id = (blockIdx.y << 6) | blockIdx.x;
  const int s = (id & 7) * (gridDim.y << 3) + (id >> 3);
  const int b = blockIdx.z, h = s >> 6, n0 = (s & 63) * 64;
  const u16* Kb = Kl + (size_t)b * 262144 + h * 64;
  const u16* Vb = VT + (size_t)b * 262144 + (size_t)(h * 64) * 256;
  u16* vbase = sm + 16384;

  auto stage_slice = [&](int sl64, int buf) {
#pragma unroll
    for (int i = 0; i < 2; ++i) {
      int u = i * 256 + t;
      int d = u >> 3, ps = u & 7;
      gload_lds16(Vb + (size_t)d * 256 + sl64 * 64 + (ps ^ (d & 7)) * 8,
                  vbase + buf * 4096 + i * 2048 + t * 8);
    }
  };

#pragma unroll
  for (int p = 0; p < 8; ++p) {
    int row = p * 32 + (t >> 3);
    int ls = ((t & 7) + 8 - (row & 7)) & 7;
    gload_lds16(Kb + (size_t)row * 1024 + ls * 8, sm + p * 2048 + w * 512);
  }
  stage_slice(0, 0);
  stage_slice(1, 1);
  const int qrow = n0 + w * 16 + r;
  const u16* Qp = Q + ((size_t)(b * 4096 + qrow)) * 1024 + h * 64 + g * 8;
  bf16x8 aq0 = *(const bf16x8*)Qp;
  bf16x8 aq1 = *(const bf16x8*)(Qp + 32);
  asm volatile("s_waitcnt vmcnt(4)" ::: "memory");
  __builtin_amdgcn_s_barrier();

  f32x4 dotv[16];
  __builtin_amdgcn_s_setprio(1);
#pragma unroll
  for (int kf = 0; kf < 16; ++kf) {
    int row = kf * 16 + r;
    bf16x8 kb0 = *(const bf16x8*)&sm[row * 64 + ((g + row) & 7) * 8];
    bf16x8 kb1 = *(const bf16x8*)&sm[row * 64 + ((4 + g + row) & 7) * 8];
    f32x4 d = f32x4{0.f, 0.f, 0.f, 0.f};
    d = mfma16(kb0, aq0, d);
    d = mfma16(kb1, aq1, d);
    dotv[kf] = d;
  }
  __builtin_amdgcn_s_setprio(0);
  asm volatile("s_waitcnt vmcnt(2)" ::: "memory");
  __builtin_amdgcn_s_barrier();

  float mx = -3.4e38f;
#pragma unroll
  for (int kf = 0; kf < 16; ++kf)
    mx = fmaxf(mx, fmaxf(fmaxf(dotv[kf][0], dotv[kf][1]), fmaxf(dotv[kf][2], dotv[kf][3])));
  mx = fmaxf(mx, __shfl_xor(mx, 16, 64));
  mx = fmaxf(mx, __shfl_xor(mx, 32, 64));
  float ssum = 0.f;
#pragma unroll
  for (int kf = 0; kf < 16; ++kf)
#pragma unroll
    for (int j = 0; j < 4; ++j) {
      float p = __builtin_amdgcn_exp2f(dotv[kf][j] - mx);
      dotv[kf][j] = p;
      ssum += p;
    }
  ssum += __shfl_xor(ssum, 16, 64);
  ssum += __shfl_xor(ssum, 32, 64);
  const float inv = 1.f / ssum;
  float invv[4];
#pragma unroll
  for (int rr = 0; rr < 4; ++rr) invv[rr] = __shfl(inv, 4 * g + rr, 64);

  const int q16 = w * 16 + r;
  const int qx = (q16 & 7) << 3;
#pragma unroll
  for (int kf = 0; kf < 16; ++kf) {
    uint2 val;
    val.x = pk2(dotv[kf][0], dotv[kf][1]);
    val.y = pk2(dotv[kf][2], dotv[kf][3]);
    *(uint2*)&sm[(q16 * 256 + kf * 16 + 4 * g) ^ qx] = val;
  }

  f32x4 oacc[4];
#pragma unroll
  for (int df = 0; df < 4; ++df) oacc[df] = f32x4{0.f, 0.f, 0.f, 0.f};
#pragma unroll
  for (int ph = 0; ph < 4; ++ph) {
    const u16* vb = vbase + (ph & 1) * 4096;
    __builtin_amdgcn_s_setprio(1);
#pragma unroll
    for (int kk2 = 0; kk2 < 2; ++kk2) {
      int kk = ph * 2 + kk2;
      bf16x8 ap = *(const bf16x8*)&sm[(q16 * 256 + kk * 32 + g * 8) ^ qx];
#pragma unroll
      for (int df = 0; df < 4; ++df) {
        int d = df * 16 + r;
        bf16x8 bv = *(const bf16x8*)&vb[d * 64 + ((kk2 * 4 + g) ^ (d & 7)) * 8];
        oacc[df] = mfma16(ap, bv, oacc[df]);
      }
    }
    __builtin_amdgcn_s_setprio(0);
    if (ph < 3) {
      asm volatile("s_waitcnt vmcnt(0)" ::: "memory");
      __builtin_amdgcn_s_barrier();
      if (ph < 2) stage_slice(ph + 2, ph & 1);
    }
  }

  u16* myO = sm + w * 4096;
#pragma unroll
  for (int df = 0; df < 4; ++df)
#pragma unroll
    for (int rr = 0; rr < 4; ++rr) {
      int row = 4 * g + rr;
      int col = df * 16 + r;
      myO[row * 64 + (((col >> 3) ^ (row & 7)) << 3) + (col & 7)] = f2bf(oacc[df][rr] * invv[rr]);
    }
#pragma unroll
  for (int i = 0; i < 2; ++i) {
    int idx = i * 64 + lane;
    int row = idx >> 3, c8 = idx & 7;
    bf16x8 v = *(const bf16x8*)&myO[row * 64 + ((c8 ^ (row & 7)) << 3)];
    *(bf16x8*)&Out[((size_t)(b * 4096 + n0 + w * 16 + row)) * 1024 + h * 64 + c8 * 8] = v;
  }
}

extern "C" void kernel_launch(void* const* d_in, const int* in_sizes, int n_in,
                              void* d_out, int out_size, void* d_ws, size_t ws_size,
                              hipStream_t stream) {
  const float* x  = (const float*)d_in[0];
  const float* Wq = (const float*)d_in[1];
  const float* Wk = (const float*)d_in[2];
  const float* Wv = (const float*)d_in[3];
  const float* pk = (const float*)d_in[4];
  const float* pv = (const float*)d_in[5];
  const float* Wo = (const float*)d_in[6];
  const float* bo = (const float*)d_in[7];

  u16* ws = (u16*)d_ws;
  u16* xbf   = ws;                   // [4][4096][1024]
  u16* xT    = xbf + 16777216;       // [4][1024][4096] == xT_flat [4096][4096]
  u16* wqb   = xT + 16777216;        // [1024][1024]
  u16* wkb   = wqb + 1048576;
  u16* wvb   = wkb + 1048576;
  u16* wob   = wvb + 1048576;
  u16* projT = wob + 1048576;        // [512][4096] (k rows 0-255, v rows 256-511)
  u16* Qb    = projT + 2097152;      // [16384][1024]; holds xp fp32 partials first
  u16* xp    = Qb + 16777216;        // [512][4096] bf16
  u16* klow  = xp + 2097152;         // [4][256][1024]
  u16* vT    = klow + 1048576;       // [4][1024][256]
  u16* aout  = xbf;                  // reuse after Q GEMM
  float* xp_part = (float*)Qb;       // [4 z][512][4096] fp32

  // 1) x: convert + row-major bf16 + transpose (one read of x)
  cvt_xpose_kernel<<<dim3(16, 64, 4), 256, 0, stream>>>(x, xbf, xT, 4096, 1024,
                                                        4194304, 4194304, 4194304);
  // 2) weights + proj transposes merged
  cvt_misc_kernel<<<dim3(1024, 6), 256, 0, stream>>>(Wq, Wk, Wv, Wo, wqb, wkb, wvb, wob,
                                                     pk, pv, projT);
  // 3) xp partials: ONE GEMM M=512, N=4096, K=4096, split-K x4
  gemm_bt_kernel<2><<<dim3(32, 4, 4), 256, 0, stream>>>(
      projT, xT, nullptr, (void*)xp_part, nullptr, nullptr, 1.f,
      4096, 4096, 4096, 1024, 0, 0, 2097152, 1, 1024, 1024);
  // 4) reduce partials -> xp bf16 [512][4096]
  reduce4_kernel<<<2048, 256, 0, stream>>>(xp_part, xp);
  // 5) kv: z = b'*2 + half; K half -> klow row-major, V half -> vT transposed
  gemm_bt_kernel<3><<<dim3(8, 2, 8), 256, 0, stream>>>(
      xp, wkb, wvb, (void*)klow, vT, nullptr, 1.f,
      4096, 1024, 1024, 1024, 1048576, 0, 262144, 2, 1024, 0);
  // 6) Q = (x @ Wq^T) * QSCALE — 256x128 high-intensity kernel
  qgemm_kernel<0><<<dim3(8, 64), 256, 0, stream>>>(
      xbf, wqb, (void*)Qb, nullptr, QSCALE, 1024, 1024, 1024, 1024);
  // 7) attention
  attn_kernel<<<dim3(64, 16, 4), 256, 0, stream>>>(Qb, klow, vT, aout);
  // 8) final = attn_out @ Wo^T + bo -> fp32 d_out — 256x128 high-intensity kernel
  qgemm_kernel<1><<<dim3(8, 64), 256, 0, stream>>>(
      aout, wob, d_out, bo, 1.f, 1024, 1024, 1024, 1024);
}

// Round 16
// 205.546 us; speedup vs baseline: 1.0560x; 1.0560x over previous
//
#include <hip/hip_runtime.h>
#include <hip/hip_bf16.h>
#include <stdint.h>

typedef unsigned short u16;
typedef __attribute__((ext_vector_type(8))) short bf16x8;   // 8 bf16 = 4 VGPRs
typedef __attribute__((ext_vector_type(4))) float f32x4;

#define DEV __device__ __forceinline__

DEV u16 f2bf(float f) {
  union { float f; unsigned u; } v; v.f = f;
  unsigned r = (v.u + 0x7fffu + ((v.u >> 16) & 1u)) >> 16;   // RNE
  return (u16)r;
}

DEV float bf2f(u16 h) {
  union { unsigned u; float f; } v; v.u = ((unsigned)h) << 16;
  return v.f;
}

// packed 2x f32 -> 2x bf16 (v_cvt_pk_bf16_f32), RNE
DEV unsigned pk2(float lo, float hi) {
  union { __hip_bfloat162 h; unsigned u; } c;
  c.h = __float22bfloat162_rn(make_float2(lo, hi));
  return c.u;
}

DEV f32x4 mfma16(bf16x8 a, bf16x8 b, f32x4 c) {
  return __builtin_amdgcn_mfma_f32_16x16x32_bf16(a, b, c, 0, 0, 0);
}

DEV void gload_lds16(const u16* g, u16* l) {
  __builtin_amdgcn_global_load_lds((const __attribute__((address_space(1))) void*)g,
                                   (__attribute__((address_space(3))) void*)l, 16, 0, 0);
}

// softmax logit pre-scale folded into Q: dh^-0.5 (=1/8) * log2(e), so exp = exp2
#define QSCALE 0.18033688011112042f

// ---------------- fused fp32 -> bf16 convert (+ optional row-major copy) + transpose ----------------
__global__ void cvt_xpose_kernel(const float* __restrict__ src, u16* __restrict__ dst_rm,
                                 u16* __restrict__ dst_tp, int R, int C,
                                 long zS, long zRM, long zTP) {
  __shared__ u16 tile[64][72];
  src += (size_t)blockIdx.z * zS;
  dst_tp += (size_t)blockIdx.z * zTP;
  int r0 = blockIdx.y * 64, c0 = blockIdx.x * 64;
  int tr = threadIdx.x >> 2, tc = (threadIdx.x & 3) * 16;
  const float* s = src + (size_t)(r0 + tr) * C + c0 + tc;
  u16 loc[16];
#pragma unroll
  for (int q = 0; q < 4; ++q) {
    float4 v = ((const float4*)s)[q];
    loc[q * 4 + 0] = f2bf(v.x); loc[q * 4 + 1] = f2bf(v.y);
    loc[q * 4 + 2] = f2bf(v.z); loc[q * 4 + 3] = f2bf(v.w);
  }
#pragma unroll
  for (int i = 0; i < 16; ++i) tile[tr][tc + i] = loc[i];
  if (dst_rm) {
    u16* d = dst_rm + (size_t)blockIdx.z * zRM + (size_t)(r0 + tr) * C + c0 + tc;
    *(bf16x8*)d = *(const bf16x8*)&loc[0];
    *(bf16x8*)(d + 8) = *(const bf16x8*)&loc[8];
  }
  __syncthreads();
  u16 tmp[16];
#pragma unroll
  for (int i = 0; i < 16; ++i) tmp[i] = tile[tc + i][tr];
  u16* d = dst_tp + (size_t)(c0 + tr) * R + r0 + tc;
  *(bf16x8*)d = *(const bf16x8*)&tmp[0];
  *(bf16x8*)(d + 8) = *(const bf16x8*)&tmp[8];
}

// ---------------- merged: 4 weight converts (y 0-3) + proj_k/proj_v transposes (y 4-5) ----------------
__global__ void cvt_misc_kernel(const float* __restrict__ s0, const float* __restrict__ s1,
                                const float* __restrict__ s2, const float* __restrict__ s3,
                                u16* __restrict__ d0, u16* __restrict__ d1,
                                u16* __restrict__ d2, u16* __restrict__ d3,
                                const float* __restrict__ pk, const float* __restrict__ pv,
                                u16* __restrict__ projT) {
  __shared__ u16 tile[64][72];
  const int y = blockIdx.y;
  if (y < 4) {
    const float* s; u16* d;
    switch (y) {
      case 0: s = s0; d = d0; break;
      case 1: s = s1; d = d1; break;
      case 2: s = s2; d = d2; break;
      default: s = s3; d = d3; break;
    }
    int i = blockIdx.x * 256 + threadIdx.x;
    float4 v = ((const float4*)s)[i];
    ushort4 o; o.x = f2bf(v.x); o.y = f2bf(v.y); o.z = f2bf(v.z); o.w = f2bf(v.w);
    ((ushort4*)d)[i] = o;
    return;
  }
  if (blockIdx.x >= 256) return;
  const float* src = (y == 4) ? pk : pv;
  u16* dst = projT + (size_t)(y - 4) * 1048576;
  int r0 = (blockIdx.x >> 2) * 64, c0 = (blockIdx.x & 3) * 64;
  int tr = threadIdx.x >> 2, tc = (threadIdx.x & 3) * 16;
  const float* s = src + (size_t)(r0 + tr) * 256 + c0 + tc;
  u16 loc[16];
#pragma unroll
  for (int q = 0; q < 4; ++q) {
    float4 v = ((const float4*)s)[q];
    loc[q * 4 + 0] = f2bf(v.x); loc[q * 4 + 1] = f2bf(v.y);
    loc[q * 4 + 2] = f2bf(v.z); loc[q * 4 + 3] = f2bf(v.w);
  }
#pragma unroll
  for (int i = 0; i < 16; ++i) tile[tr][tc + i] = loc[i];
  __syncthreads();
  u16 tmp[16];
#pragma unroll
  for (int i = 0; i < 16; ++i) tmp[i] = tile[tc + i][tr];
  u16* d = dst + (size_t)(c0 + tr) * 4096 + r0 + tc;
  *(bf16x8*)d = *(const bf16x8*)&tmp[0];
  *(bf16x8*)(d + 8) = *(const bf16x8*)&tmp[8];
}

// ---------------- split-K reduce: 4x bf16 partials -> bf16, fp32 accum ----------------
__global__ void reduce4_kernel(const u16* __restrict__ part, u16* __restrict__ out) {
  int i = blockIdx.x * 256 + threadIdx.x;   // bf16x8 unit; total 262144 units
  bf16x8 a = ((const bf16x8*)part)[i];
  bf16x8 b = ((const bf16x8*)part)[i + 262144];
  bf16x8 c = ((const bf16x8*)part)[i + 524288];
  bf16x8 d = ((const bf16x8*)part)[i + 786432];
  u16 o[8];
#pragma unroll
  for (int j = 0; j < 8; ++j)
    o[j] = f2bf(bf2f((u16)a[j]) + bf2f((u16)b[j]) + bf2f((u16)c[j]) + bf2f((u16)d[j]));
  ((bf16x8*)out)[i] = *(const bf16x8*)&o[0];
}

// ------------- 128x128 2-phase GEMM (xp split-K and kv) -------------
// OMODE: 3 = kv mode (even z row-major bf16, odd z transposed bf16 into CoutT);
//        4 = bf16 raw partial at z*zC, LDS-staged coalesced stores.
template<int OMODE>
__global__ __launch_bounds__(256, 4)
void gemm_bt_kernel(const u16* __restrict__ A, const u16* __restrict__ Bt,
                    const u16* __restrict__ Bt2, void* __restrict__ Cout,
                    u16* __restrict__ CoutT, const float* __restrict__ bias, float cscale,
                    int ldA, int ldB, int ldC, int Klen,
                    long zA, long zB, long zC, int bMod, long kChunkA, long kChunkB) {
  __shared__ __align__(16) u16 smA[2][128 * 32];
  __shared__ __align__(16) u16 smB[2][128 * 32];
  const int t = threadIdx.x;
  const int lane = t & 63, wave = t >> 6;
  const int wm = wave & 1, wn = wave >> 1;
  const int g = lane >> 4, r = lane & 15;
  const int id = blockIdx.y * gridDim.x + blockIdx.x;
  const int cpx = (gridDim.x * gridDim.y) >> 3;
  const int s = (id & 7) * cpx + (id >> 3);
  const int bx = s % gridDim.x, by = s / gridDim.x;
  const int z = blockIdx.z;
  const int b = z % bMod, kc = z / bMod;
  const u16* Ab = A + (size_t)b * zA + (size_t)kc * kChunkA;
  const u16* Bbase = (Bt2 && (b & 1)) ? Bt2 : Bt;
  const u16* Bb = Bbase + (size_t)b * zB + (size_t)kc * kChunkB;
  const int m0 = by * 128, n0 = bx * 128;
  const int srow = t >> 2;
  const int lslot = ((t & 3) + 4 - ((srow >> 1) & 3)) & 3;

  f32x4 acc[4][4];
#pragma unroll
  for (int m = 0; m < 4; ++m)
#pragma unroll
    for (int n = 0; n < 4; ++n) acc[m][n] = f32x4{0.f, 0.f, 0.f, 0.f};

  auto STAGE = [&](int buf, int k0) {
#pragma unroll
    for (int p = 0; p < 2; ++p) {
      int row = p * 64 + srow;
      gload_lds16(Ab + (size_t)(m0 + row) * ldA + k0 + lslot * 8, &smA[buf][p * 2048 + wave * 512]);
      gload_lds16(Bb + (size_t)(n0 + row) * ldB + k0 + lslot * 8, &smB[buf][p * 2048 + wave * 512]);
    }
  };

  const int nt = Klen >> 5;
  STAGE(0, 0);
  __syncthreads();
  int cur = 0;
  for (int it = 0; it < nt; ++it) {
    if (it + 1 < nt) STAGE(cur ^ 1, (it + 1) << 5);
    bf16x8 af[4], bfr[4];
#pragma unroll
    for (int m = 0; m < 4; ++m) {
      int row = wm * 64 + m * 16 + r;
      int ps = (g + (row >> 1)) & 3;
      af[m] = *(const bf16x8*)&smA[cur][row * 32 + ps * 8];
    }
#pragma unroll
    for (int n = 0; n < 4; ++n) {
      int row = wn * 64 + n * 16 + r;
      int ps = (g + (row >> 1)) & 3;
      bfr[n] = *(const bf16x8*)&smB[cur][row * 32 + ps * 8];
    }
#pragma unroll
    for (int m = 0; m < 4; ++m)
#pragma unroll
      for (int n = 0; n < 4; ++n)
        acc[m][n] = mfma16(af[m], bfr[n], acc[m][n]);
    __syncthreads();
    cur ^= 1;
  }

  if constexpr (OMODE == 4) {
    // bf16 partial: per-wave 64x64 u16 tile in LDS (8 KB/wave x 4 = 32 KB), 16B stores
    u16* myT = (u16*)&smA[0][0] + wave * 4096;
    u16* Cg = (u16*)Cout + (size_t)z * zC + (size_t)(m0 + wm * 64) * ldC + n0 + wn * 64;
#pragma unroll
    for (int m = 0; m < 4; ++m)
#pragma unroll
      for (int n = 0; n < 4; ++n)
#pragma unroll
        for (int rr = 0; rr < 4; ++rr) {
          int rl = m * 16 + 4 * g + rr;
          int cl = n * 16 + r;
          myT[rl * 64 + (((cl >> 3) ^ (rl & 7)) << 3) + (cl & 7)] = f2bf(acc[m][n][rr]);
        }
    // same-wave write->read: lgkm ordering, no barrier needed
#pragma unroll
    for (int i = 0; i < 8; ++i) {
      int idx = i * 64 + lane;
      int row = idx >> 3, c8 = idx & 7;
      bf16x8 v = *(const bf16x8*)&myT[row * 64 + ((c8 ^ (row & 7)) << 3)];
      *(bf16x8*)&Cg[(size_t)row * ldC + c8 * 8] = v;
    }
  } else {  // OMODE == 3
    if ((z & 1) == 0) {
      u16* C = (u16*)Cout + (size_t)(z >> 1) * zC;
#pragma unroll
      for (int n = 0; n < 4; ++n) {
        int col = n0 + wn * 64 + n * 16 + r;
#pragma unroll
        for (int m = 0; m < 4; ++m) {
          int rowb = m0 + wm * 64 + m * 16 + 4 * g;
#pragma unroll
          for (int rr = 0; rr < 4; ++rr)
            C[(size_t)(rowb + rr) * ldC + col] = f2bf(acc[m][n][rr]);
        }
      }
    } else {
      u16* C = CoutT + (size_t)(z >> 1) * zC;
#pragma unroll
      for (int n = 0; n < 4; ++n) {
        int col = n0 + wn * 64 + n * 16 + r;
#pragma unroll
        for (int m = 0; m < 4; ++m) {
          int rowb = m0 + wm * 64 + m * 16 + 4 * g;
          ushort4 o;
          o.x = f2bf(acc[m][n][0]); o.y = f2bf(acc[m][n][1]);
          o.z = f2bf(acc[m][n][2]); o.w = f2bf(acc[m][n][3]);
          *(ushort4*)&C[(size_t)col * 256 + rowb] = o;
        }
      }
    }
  }
}

// ------------- 128x256 GEMM, 3-deep ring + counted vmcnt, 2 WGs/CU (R13 best; setprio removed) -------------
template<int OMODE>
__global__ __launch_bounds__(512, 4)
void qgemm128_kernel(const u16* __restrict__ A, const u16* __restrict__ Bt,
                     void* __restrict__ Cout, const float* __restrict__ bias,
                     float cscale, int ldA, int ldB, int ldC, int Klen) {
  __shared__ __align__(16) u16 lds[36864];   // 72 KB
  const int t = threadIdx.x;
  const int lane = t & 63, wave = t >> 6;
  const int g = lane >> 4, r = lane & 15;
  const int wm = wave >> 2, wn = wave & 3;
  const int id = blockIdx.y * gridDim.x + blockIdx.x;
  const int cpx = (gridDim.x * gridDim.y) >> 3;
  const int s = (id & 7) * cpx + (id >> 3);
  const int bx = s & 3, by = s >> 2;
  const int m0 = by * 128, n0 = bx * 256;

  const int srow = t >> 2;
  const int lslot = ((t & 3) + 4 - ((srow >> 1) & 3)) & 3;

  auto STAGE = [&](int buf, int k0) {
    gload_lds16(A + (size_t)(m0 + srow) * ldA + k0 + lslot * 8,
                lds + buf * 4096 + t * 8);
#pragma unroll
    for (int p = 0; p < 2; ++p)
      gload_lds16(Bt + (size_t)(n0 + p * 128 + srow) * ldB + k0 + lslot * 8,
                  lds + 12288 + buf * 8192 + p * 4096 + t * 8);
  };

  f32x4 acc[4][4];
#pragma unroll
  for (int m = 0; m < 4; ++m)
#pragma unroll
    for (int n = 0; n < 4; ++n) acc[m][n] = f32x4{0.f, 0.f, 0.f, 0.f};

  const int nt = Klen >> 5;
  STAGE(0, 0);
  STAGE(1, 32);
  asm volatile("s_waitcnt vmcnt(3)" ::: "memory");
  __builtin_amdgcn_s_barrier();

  int cur = 0;
  for (int it = 0; it < nt; ++it) {
    int pre = cur + 2; if (pre >= 3) pre -= 3;
    if (it + 2 < nt) STAGE(pre, (it + 2) << 5);
    const u16* Ab = lds + cur * 4096;
    const u16* Bb = lds + 12288 + cur * 8192;
    bf16x8 af[4], bfr[4];
#pragma unroll
    for (int m = 0; m < 4; ++m) {
      int row = wm * 64 + m * 16 + r;
      int ps = (g + (row >> 1)) & 3;
      af[m] = *(const bf16x8*)&Ab[row * 32 + ps * 8];
    }
#pragma unroll
    for (int n = 0; n < 4; ++n) {
      int row = wn * 64 + n * 16 + r;
      int ps = (g + (row >> 1)) & 3;
      bfr[n] = *(const bf16x8*)&Bb[row * 32 + ps * 8];
    }
#pragma unroll
    for (int m = 0; m < 4; ++m)
#pragma unroll
      for (int n = 0; n < 4; ++n)
        acc[m][n] = mfma16(af[m], bfr[n], acc[m][n]);
    if (it + 1 < nt) {
      if (it + 2 < nt) asm volatile("s_waitcnt vmcnt(3)" ::: "memory");
      else             asm volatile("s_waitcnt vmcnt(0)" ::: "memory");
      __builtin_amdgcn_s_barrier();
    }
    cur = cur + 1; if (cur >= 3) cur -= 3;
  }
  __builtin_amdgcn_s_barrier();

  if constexpr (OMODE == 0) {
    u16* myT = lds + wave * 2048;
    u16* Cg = (u16*)Cout + (size_t)(m0 + wm * 64) * ldC + n0 + wn * 64;
#pragma unroll
    for (int np = 0; np < 2; ++np) {
#pragma unroll
      for (int n2 = 0; n2 < 2; ++n2)
#pragma unroll
        for (int m = 0; m < 4; ++m)
#pragma unroll
          for (int rr = 0; rr < 4; ++rr) {
            int rl = m * 16 + 4 * g + rr;
            int cl = n2 * 16 + r;
            myT[rl * 32 + (((cl >> 3) ^ (rl & 3)) << 3) + (cl & 7)] =
                f2bf(acc[m][np * 2 + n2][rr] * cscale);
          }
#pragma unroll
      for (int i = 0; i < 4; ++i) {
        int idx = i * 64 + lane;
        int row = idx >> 2, c = idx & 3;
        bf16x8 v = *(const bf16x8*)&myT[row * 32 + ((c ^ (row & 3)) << 3)];
        *(bf16x8*)&Cg[(size_t)row * ldC + np * 32 + c * 8] = v;
      }
    }
  } else {
    float* myF = (float*)lds + wave * 2048;
    float bvn[4];
#pragma unroll
    for (int n = 0; n < 4; ++n) bvn[n] = bias[n0 + wn * 64 + n * 16 + r];
    float* Cg = (float*)Cout + (size_t)(m0 + wm * 64) * ldC + n0 + wn * 64;
#pragma unroll
    for (int np = 0; np < 2; ++np) {
#pragma unroll
      for (int n2 = 0; n2 < 2; ++n2)
#pragma unroll
        for (int m = 0; m < 4; ++m)
#pragma unroll
          for (int rr = 0; rr < 4; ++rr) {
            int rl = m * 16 + 4 * g + rr;
            int cl = n2 * 16 + r;
            myF[rl * 32 + ((((cl >> 2) ^ (rl & 7)) & 7) << 2) + (cl & 3)] =
                acc[m][np * 2 + n2][rr] + bvn[np * 2 + n2];
          }
#pragma unroll
      for (int i = 0; i < 8; ++i) {
        int idx = i * 64 + lane;
        int row = idx >> 3, c = idx & 7;
        float4 v = *(const float4*)&myF[row * 32 + (((c ^ (row & 7)) & 7) << 2)];
        *(float4*)&Cg[(size_t)row * ldC + np * 32 + c * 4] = v;
      }
    }
  }
}

// ------------- fused attention (frozen from R14) -------------
__global__ __launch_bounds__(256, 3)
void attn_kernel(const u16* __restrict__ Q, const u16* __restrict__ Kl,
                 const u16* __restrict__ VT, u16* __restrict__ Out) {
  __shared__ __align__(16) u16 sm[24576];   // 48 KB
  const int t = threadIdx.x, lane = t & 63, w = t >> 6;
  const int g = lane >> 4, r = lane & 15;
  const int id = (blockIdx.y << 6) | blockIdx.x;
  const int s = (id & 7) * (gridDim.y << 3) + (id >> 3);
  const int b = blockIdx.z, h = s >> 6, n0 = (s & 63) * 64;
  const u16* Kb = Kl + (size_t)b * 262144 + h * 64;
  const u16* Vb = VT + (size_t)b * 262144 + (size_t)(h * 64) * 256;
  u16* vbase = sm + 16384;

  auto stage_slice = [&](int sl64, int buf) {
#pragma unroll
    for (int i = 0; i < 2; ++i) {
      int u = i * 256 + t;
      int d = u >> 3, ps = u & 7;
      gload_lds16(Vb + (size_t)d * 256 + sl64 * 64 + (ps ^ (d & 7)) * 8,
                  vbase + buf * 4096 + i * 2048 + t * 8);
    }
  };

#pragma unroll
  for (int p = 0; p < 8; ++p) {
    int row = p * 32 + (t >> 3);
    int ls = ((t & 7) + 8 - (row & 7)) & 7;
    gload_lds16(Kb + (size_t)row * 1024 + ls * 8, sm + p * 2048 + w * 512);
  }
  stage_slice(0, 0);
  stage_slice(1, 1);
  const int qrow = n0 + w * 16 + r;
  const u16* Qp = Q + ((size_t)(b * 4096 + qrow)) * 1024 + h * 64 + g * 8;
  bf16x8 aq0 = *(const bf16x8*)Qp;
  bf16x8 aq1 = *(const bf16x8*)(Qp + 32);
  asm volatile("s_waitcnt vmcnt(4)" ::: "memory");
  __builtin_amdgcn_s_barrier();

  f32x4 dotv[16];
  __builtin_amdgcn_s_setprio(1);
#pragma unroll
  for (int kf = 0; kf < 16; ++kf) {
    int row = kf * 16 + r;
    bf16x8 kb0 = *(const bf16x8*)&sm[row * 64 + ((g + row) & 7) * 8];
    bf16x8 kb1 = *(const bf16x8*)&sm[row * 64 + ((4 + g + row) & 7) * 8];
    f32x4 d = f32x4{0.f, 0.f, 0.f, 0.f};
    d = mfma16(kb0, aq0, d);
    d = mfma16(kb1, aq1, d);
    dotv[kf] = d;
  }
  __builtin_amdgcn_s_setprio(0);
  asm volatile("s_waitcnt vmcnt(2)" ::: "memory");
  __builtin_amdgcn_s_barrier();

  float mx = -3.4e38f;
#pragma unroll
  for (int kf = 0; kf < 16; ++kf)
    mx = fmaxf(mx, fmaxf(fmaxf(dotv[kf][0], dotv[kf][1]), fmaxf(dotv[kf][2], dotv[kf][3])));
  mx = fmaxf(mx, __shfl_xor(mx, 16, 64));
  mx = fmaxf(mx, __shfl_xor(mx, 32, 64));
  float ssum = 0.f;
#pragma unroll
  for (int kf = 0; kf < 16; ++kf)
#pragma unroll
    for (int j = 0; j < 4; ++j) {
      float p = __builtin_amdgcn_exp2f(dotv[kf][j] - mx);
      dotv[kf][j] = p;
      ssum += p;
    }
  ssum += __shfl_xor(ssum, 16, 64);
  ssum += __shfl_xor(ssum, 32, 64);
  const float inv = 1.f / ssum;
  float invv[4];
#pragma unroll
  for (int rr = 0; rr < 4; ++rr) invv[rr] = __shfl(inv, 4 * g + rr, 64);

  const int q16 = w * 16 + r;
  const int qx = (q16 & 7) << 3;
#pragma unroll
  for (int kf = 0; kf < 16; ++kf) {
    uint2 val;
    val.x = pk2(dotv[kf][0], dotv[kf][1]);
    val.y = pk2(dotv[kf][2], dotv[kf][3]);
    *(uint2*)&sm[(q16 * 256 + kf * 16 + 4 * g) ^ qx] = val;
  }

  f32x4 oacc[4];
#pragma unroll
  for (int df = 0; df < 4; ++df) oacc[df] = f32x4{0.f, 0.f, 0.f, 0.f};
#pragma unroll
  for (int ph = 0; ph < 4; ++ph) {
    const u16* vb = vbase + (ph & 1) * 4096;
    __builtin_amdgcn_s_setprio(1);
#pragma unroll
    for (int kk2 = 0; kk2 < 2; ++kk2) {
      int kk = ph * 2 + kk2;
      bf16x8 ap = *(const bf16x8*)&sm[(q16 * 256 + kk * 32 + g * 8) ^ qx];
#pragma unroll
      for (int df = 0; df < 4; ++df) {
        int d = df * 16 + r;
        bf16x8 bv = *(const bf16x8*)&vb[d * 64 + ((kk2 * 4 + g) ^ (d & 7)) * 8];
        oacc[df] = mfma16(ap, bv, oacc[df]);
      }
    }
    __builtin_amdgcn_s_setprio(0);
    if (ph < 3) {
      asm volatile("s_waitcnt vmcnt(0)" ::: "memory");
      __builtin_amdgcn_s_barrier();
      if (ph < 2) stage_slice(ph + 2, ph & 1);
    }
  }

  u16* myO = sm + w * 4096;
#pragma unroll
  for (int df = 0; df < 4; ++df)
#pragma unroll
    for (int rr = 0; rr < 4; ++rr) {
      int row = 4 * g + rr;
      int col = df * 16 + r;
      myO[row * 64 + (((col >> 3) ^ (row & 7)) << 3) + (col & 7)] = f2bf(oacc[df][rr] * invv[rr]);
    }
#pragma unroll
  for (int i = 0; i < 2; ++i) {
    int idx = i * 64 + lane;
    int row = idx >> 3, c8 = idx & 7;
    bf16x8 v = *(const bf16x8*)&myO[row * 64 + ((c8 ^ (row & 7)) << 3)];
    *(bf16x8*)&Out[((size_t)(b * 4096 + n0 + w * 16 + row)) * 1024 + h * 64 + c8 * 8] = v;
  }
}

extern "C" void kernel_launch(void* const* d_in, const int* in_sizes, int n_in,
                              void* d_out, int out_size, void* d_ws, size_t ws_size,
                              hipStream_t stream) {
  const float* x  = (const float*)d_in[0];
  const float* Wq = (const float*)d_in[1];
  const float* Wk = (const float*)d_in[2];
  const float* Wv = (const float*)d_in[3];
  const float* pk = (const float*)d_in[4];
  const float* pv = (const float*)d_in[5];
  const float* Wo = (const float*)d_in[6];
  const float* bo = (const float*)d_in[7];

  u16* ws = (u16*)d_ws;
  u16* xbf   = ws;                   // [4][4096][1024]
  u16* xT    = xbf + 16777216;       // [4][1024][4096] == xT_flat [4096][4096]
  u16* wqb   = xT + 16777216;        // [1024][1024]
  u16* wkb   = wqb + 1048576;
  u16* wvb   = wkb + 1048576;
  u16* wob   = wvb + 1048576;
  u16* projT = wob + 1048576;        // [512][4096] (k rows 0-255, v rows 256-511)
  u16* Qb    = projT + 2097152;      // [16384][1024]; holds xp bf16 partials first
  u16* xp    = Qb + 16777216;        // [512][4096] bf16
  u16* klow  = xp + 2097152;         // [4][256][1024]
  u16* vT    = klow + 1048576;       // [4][1024][256]
  u16* aout  = xbf;                  // reuse after Q GEMM
  u16* xp_part = Qb;                 // [4 z][512][4096] bf16 = 16.8 MB (in Qb region)

  // 1) x: convert + row-major bf16 + transpose (one read of x)
  cvt_xpose_kernel<<<dim3(16, 64, 4), 256, 0, stream>>>(x, xbf, xT, 4096, 1024,
                                                        4194304, 4194304, 4194304);
  // 2) weights + proj transposes merged
  cvt_misc_kernel<<<dim3(1024, 6), 256, 0, stream>>>(Wq, Wk, Wv, Wo, wqb, wkb, wvb, wob,
                                                     pk, pv, projT);
  // 3) xp partials (bf16): ONE GEMM M=512, N=4096, K=4096, split-K x4
  gemm_bt_kernel<4><<<dim3(32, 4, 4), 256, 0, stream>>>(
      projT, xT, nullptr, (void*)xp_part, nullptr, nullptr, 1.f,
      4096, 4096, 4096, 1024, 0, 0, 2097152, 1, 1024, 1024);
  // 4) reduce bf16 partials -> xp bf16 [512][4096]
  reduce4_kernel<<<1024, 256, 0, stream>>>(xp_part, xp);
  // 5) kv: z = b'*2 + half; K half -> klow row-major, V half -> vT transposed
  gemm_bt_kernel<3><<<dim3(8, 2, 8), 256, 0, stream>>>(
      xp, wkb, wvb, (void*)klow, vT, nullptr, 1.f,
      4096, 1024, 1024, 1024, 1048576, 0, 262144, 2, 1024, 0);
  // 6) Q = (x @ Wq^T) * QSCALE — 3-deep-ring 128x256 kernel (R13 best)
  qgemm128_kernel<0><<<dim3(4, 128), 512, 0, stream>>>(
      xbf, wqb, (void*)Qb, nullptr, QSCALE, 1024, 1024, 1024, 1024);
  // 7) attention
  attn_kernel<<<dim3(64, 16, 4), 256, 0, stream>>>(Qb, klow, vT, aout);
  // 8) final = attn_out @ Wo^T + bo -> fp32 d_out — 3-deep-ring 128x256 kernel
  qgemm128_kernel<1><<<dim3(4, 128), 512, 0, stream>>>(
      aout, wob, d_out, bo, 1.f, 1024, 1024, 1024, 1024);
}

// Round 17
// 202.575 us; speedup vs baseline: 1.0715x; 1.0147x over previous
//
#include <hip/hip_runtime.h>
#include <hip/hip_bf16.h>
#include <stdint.h>

typedef unsigned short u16;
typedef __attribute__((ext_vector_type(8))) short bf16x8;   // 8 bf16 = 4 VGPRs
typedef __attribute__((ext_vector_type(4))) float f32x4;

#define DEV __device__ __forceinline__

DEV u16 f2bf(float f) {
  union { float f; unsigned u; } v; v.f = f;
  unsigned r = (v.u + 0x7fffu + ((v.u >> 16) & 1u)) >> 16;   // RNE
  return (u16)r;
}

DEV float bf2f(u16 h) {
  union { unsigned u; float f; } v; v.u = ((unsigned)h) << 16;
  return v.f;
}

// packed 2x f32 -> 2x bf16 (v_cvt_pk_bf16_f32), RNE
DEV unsigned pk2(float lo, float hi) {
  union { __hip_bfloat162 h; unsigned u; } c;
  c.h = __float22bfloat162_rn(make_float2(lo, hi));
  return c.u;
}

DEV f32x4 mfma16(bf16x8 a, bf16x8 b, f32x4 c) {
  return __builtin_amdgcn_mfma_f32_16x16x32_bf16(a, b, c, 0, 0, 0);
}

DEV void gload_lds16(const u16* g, u16* l) {
  __builtin_amdgcn_global_load_lds((const __attribute__((address_space(1))) void*)g,
                                   (__attribute__((address_space(3))) void*)l, 16, 0, 0);
}

// softmax logit pre-scale folded into Q: dh^-0.5 (=1/8) * log2(e), so exp = exp2
#define QSCALE 0.18033688011112042f

// ---------------- fused fp32 -> bf16 convert (+ optional row-major copy) + transpose ----------------
__global__ void cvt_xpose_kernel(const float* __restrict__ src, u16* __restrict__ dst_rm,
                                 u16* __restrict__ dst_tp, int R, int C,
                                 long zS, long zRM, long zTP) {
  __shared__ u16 tile[64][72];
  src += (size_t)blockIdx.z * zS;
  dst_tp += (size_t)blockIdx.z * zTP;
  int r0 = blockIdx.y * 64, c0 = blockIdx.x * 64;
  int tr = threadIdx.x >> 2, tc = (threadIdx.x & 3) * 16;
  const float* s = src + (size_t)(r0 + tr) * C + c0 + tc;
  u16 loc[16];
#pragma unroll
  for (int q = 0; q < 4; ++q) {
    float4 v = ((const float4*)s)[q];
    loc[q * 4 + 0] = f2bf(v.x); loc[q * 4 + 1] = f2bf(v.y);
    loc[q * 4 + 2] = f2bf(v.z); loc[q * 4 + 3] = f2bf(v.w);
  }
#pragma unroll
  for (int i = 0; i < 16; ++i) tile[tr][tc + i] = loc[i];
  if (dst_rm) {
    u16* d = dst_rm + (size_t)blockIdx.z * zRM + (size_t)(r0 + tr) * C + c0 + tc;
    *(bf16x8*)d = *(const bf16x8*)&loc[0];
    *(bf16x8*)(d + 8) = *(const bf16x8*)&loc[8];
  }
  __syncthreads();
  u16 tmp[16];
#pragma unroll
  for (int i = 0; i < 16; ++i) tmp[i] = tile[tc + i][tr];
  u16* d = dst_tp + (size_t)(c0 + tr) * R + r0 + tc;
  *(bf16x8*)d = *(const bf16x8*)&tmp[0];
  *(bf16x8*)(d + 8) = *(const bf16x8*)&tmp[8];
}

// ---------------- merged: 4 weight converts (y 0-3) + proj_k/proj_v transposes (y 4-5) ----------------
__global__ void cvt_misc_kernel(const float* __restrict__ s0, const float* __restrict__ s1,
                                const float* __restrict__ s2, const float* __restrict__ s3,
                                u16* __restrict__ d0, u16* __restrict__ d1,
                                u16* __restrict__ d2, u16* __restrict__ d3,
                                const float* __restrict__ pk, const float* __restrict__ pv,
                                u16* __restrict__ projT) {
  __shared__ u16 tile[64][72];
  const int y = blockIdx.y;
  if (y < 4) {
    const float* s; u16* d;
    switch (y) {
      case 0: s = s0; d = d0; break;
      case 1: s = s1; d = d1; break;
      case 2: s = s2; d = d2; break;
      default: s = s3; d = d3; break;
    }
    int i = blockIdx.x * 256 + threadIdx.x;
    float4 v = ((const float4*)s)[i];
    ushort4 o; o.x = f2bf(v.x); o.y = f2bf(v.y); o.z = f2bf(v.z); o.w = f2bf(v.w);
    ((ushort4*)d)[i] = o;
    return;
  }
  if (blockIdx.x >= 256) return;
  const float* src = (y == 4) ? pk : pv;
  u16* dst = projT + (size_t)(y - 4) * 1048576;
  int r0 = (blockIdx.x >> 2) * 64, c0 = (blockIdx.x & 3) * 64;
  int tr = threadIdx.x >> 2, tc = (threadIdx.x & 3) * 16;
  const float* s = src + (size_t)(r0 + tr) * 256 + c0 + tc;
  u16 loc[16];
#pragma unroll
  for (int q = 0; q < 4; ++q) {
    float4 v = ((const float4*)s)[q];
    loc[q * 4 + 0] = f2bf(v.x); loc[q * 4 + 1] = f2bf(v.y);
    loc[q * 4 + 2] = f2bf(v.z); loc[q * 4 + 3] = f2bf(v.w);
  }
#pragma unroll
  for (int i = 0; i < 16; ++i) tile[tr][tc + i] = loc[i];
  __syncthreads();
  u16 tmp[16];
#pragma unroll
  for (int i = 0; i < 16; ++i) tmp[i] = tile[tc + i][tr];
  u16* d = dst + (size_t)(c0 + tr) * 4096 + r0 + tc;
  *(bf16x8*)d = *(const bf16x8*)&tmp[0];
  *(bf16x8*)(d + 8) = *(const bf16x8*)&tmp[8];
}

// ---------------- split-K reduce: 4x bf16 partials -> bf16, fp32 accum ----------------
__global__ void reduce4_kernel(const u16* __restrict__ part, u16* __restrict__ out) {
  int i = blockIdx.x * 256 + threadIdx.x;   // bf16x8 unit; total 262144 units
  bf16x8 a = ((const bf16x8*)part)[i];
  bf16x8 b = ((const bf16x8*)part)[i + 262144];
  bf16x8 c = ((const bf16x8*)part)[i + 524288];
  bf16x8 d = ((const bf16x8*)part)[i + 786432];
  u16 o[8];
#pragma unroll
  for (int j = 0; j < 8; ++j)
    o[j] = f2bf(bf2f((u16)a[j]) + bf2f((u16)b[j]) + bf2f((u16)c[j]) + bf2f((u16)d[j]));
  ((bf16x8*)out)[i] = *(const bf16x8*)&o[0];
}

// ------------- 128x128 2-phase GEMM (xp split-K and kv) -------------
template<int OMODE>
__global__ __launch_bounds__(256, 4)
void gemm_bt_kernel(const u16* __restrict__ A, const u16* __restrict__ Bt,
                    const u16* __restrict__ Bt2, void* __restrict__ Cout,
                    u16* __restrict__ CoutT, const float* __restrict__ bias, float cscale,
                    int ldA, int ldB, int ldC, int Klen,
                    long zA, long zB, long zC, int bMod, long kChunkA, long kChunkB) {
  __shared__ __align__(16) u16 smA[2][128 * 32];
  __shared__ __align__(16) u16 smB[2][128 * 32];
  const int t = threadIdx.x;
  const int lane = t & 63, wave = t >> 6;
  const int wm = wave & 1, wn = wave >> 1;
  const int g = lane >> 4, r = lane & 15;
  const int id = blockIdx.y * gridDim.x + blockIdx.x;
  const int cpx = (gridDim.x * gridDim.y) >> 3;
  const int s = (id & 7) * cpx + (id >> 3);
  const int bx = s % gridDim.x, by = s / gridDim.x;
  const int z = blockIdx.z;
  const int b = z % bMod, kc = z / bMod;
  const u16* Ab = A + (size_t)b * zA + (size_t)kc * kChunkA;
  const u16* Bbase = (Bt2 && (b & 1)) ? Bt2 : Bt;
  const u16* Bb = Bbase + (size_t)b * zB + (size_t)kc * kChunkB;
  const int m0 = by * 128, n0 = bx * 128;
  const int srow = t >> 2;
  const int lslot = ((t & 3) + 4 - ((srow >> 1) & 3)) & 3;

  f32x4 acc[4][4];
#pragma unroll
  for (int m = 0; m < 4; ++m)
#pragma unroll
    for (int n = 0; n < 4; ++n) acc[m][n] = f32x4{0.f, 0.f, 0.f, 0.f};

  auto STAGE = [&](int buf, int k0) {
#pragma unroll
    for (int p = 0; p < 2; ++p) {
      int row = p * 64 + srow;
      gload_lds16(Ab + (size_t)(m0 + row) * ldA + k0 + lslot * 8, &smA[buf][p * 2048 + wave * 512]);
      gload_lds16(Bb + (size_t)(n0 + row) * ldB + k0 + lslot * 8, &smB[buf][p * 2048 + wave * 512]);
    }
  };

  const int nt = Klen >> 5;
  STAGE(0, 0);
  __syncthreads();
  int cur = 0;
  for (int it = 0; it < nt; ++it) {
    if (it + 1 < nt) STAGE(cur ^ 1, (it + 1) << 5);
    bf16x8 af[4], bfr[4];
#pragma unroll
    for (int m = 0; m < 4; ++m) {
      int row = wm * 64 + m * 16 + r;
      int ps = (g + (row >> 1)) & 3;
      af[m] = *(const bf16x8*)&smA[cur][row * 32 + ps * 8];
    }
#pragma unroll
    for (int n = 0; n < 4; ++n) {
      int row = wn * 64 + n * 16 + r;
      int ps = (g + (row >> 1)) & 3;
      bfr[n] = *(const bf16x8*)&smB[cur][row * 32 + ps * 8];
    }
#pragma unroll
    for (int m = 0; m < 4; ++m)
#pragma unroll
      for (int n = 0; n < 4; ++n)
        acc[m][n] = mfma16(af[m], bfr[n], acc[m][n]);
    __syncthreads();
    cur ^= 1;
  }

  if constexpr (OMODE == 4) {
    u16* myT = (u16*)&smA[0][0] + wave * 4096;
    u16* Cg = (u16*)Cout + (size_t)z * zC + (size_t)(m0 + wm * 64) * ldC + n0 + wn * 64;
#pragma unroll
    for (int m = 0; m < 4; ++m)
#pragma unroll
      for (int n = 0; n < 4; ++n)
#pragma unroll
        for (int rr = 0; rr < 4; ++rr) {
          int rl = m * 16 + 4 * g + rr;
          int cl = n * 16 + r;
          myT[rl * 64 + (((cl >> 3) ^ (rl & 7)) << 3) + (cl & 7)] = f2bf(acc[m][n][rr]);
        }
#pragma unroll
    for (int i = 0; i < 8; ++i) {
      int idx = i * 64 + lane;
      int row = idx >> 3, c8 = idx & 7;
      bf16x8 v = *(const bf16x8*)&myT[row * 64 + ((c8 ^ (row & 7)) << 3)];
      *(bf16x8*)&Cg[(size_t)row * ldC + c8 * 8] = v;
    }
  } else {  // OMODE == 3
    if ((z & 1) == 0) {
      u16* C = (u16*)Cout + (size_t)(z >> 1) * zC;
#pragma unroll
      for (int n = 0; n < 4; ++n) {
        int col = n0 + wn * 64 + n * 16 + r;
#pragma unroll
        for (int m = 0; m < 4; ++m) {
          int rowb = m0 + wm * 64 + m * 16 + 4 * g;
#pragma unroll
          for (int rr = 0; rr < 4; ++rr)
            C[(size_t)(rowb + rr) * ldC + col] = f2bf(acc[m][n][rr]);
        }
      }
    } else {
      u16* C = CoutT + (size_t)(z >> 1) * zC;
#pragma unroll
      for (int n = 0; n < 4; ++n) {
        int col = n0 + wn * 64 + n * 16 + r;
#pragma unroll
        for (int m = 0; m < 4; ++m) {
          int rowb = m0 + wm * 64 + m * 16 + 4 * g;
          ushort4 o;
          o.x = f2bf(acc[m][n][0]); o.y = f2bf(acc[m][n][1]);
          o.z = f2bf(acc[m][n][2]); o.w = f2bf(acc[m][n][3]);
          *(ushort4*)&C[(size_t)col * 256 + rowb] = o;
        }
      }
    }
  }
}

// ------------- 128x256 GEMM, 3-deep ring + counted vmcnt, 2 WGs/CU (R13 best; control) -------------
template<int OMODE>
__global__ __launch_bounds__(512, 4)
void qgemm128_kernel(const u16* __restrict__ A, const u16* __restrict__ Bt,
                     void* __restrict__ Cout, const float* __restrict__ bias,
                     float cscale, int ldA, int ldB, int ldC, int Klen) {
  __shared__ __align__(16) u16 lds[36864];   // 72 KB
  const int t = threadIdx.x;
  const int lane = t & 63, wave = t >> 6;
  const int g = lane >> 4, r = lane & 15;
  const int wm = wave >> 2, wn = wave & 3;
  const int id = blockIdx.y * gridDim.x + blockIdx.x;
  const int cpx = (gridDim.x * gridDim.y) >> 3;
  const int s = (id & 7) * cpx + (id >> 3);
  const int bx = s & 3, by = s >> 2;
  const int m0 = by * 128, n0 = bx * 256;

  const int srow = t >> 2;
  const int lslot = ((t & 3) + 4 - ((srow >> 1) & 3)) & 3;

  auto STAGE = [&](int buf, int k0) {
    gload_lds16(A + (size_t)(m0 + srow) * ldA + k0 + lslot * 8,
                lds + buf * 4096 + t * 8);
#pragma unroll
    for (int p = 0; p < 2; ++p)
      gload_lds16(Bt + (size_t)(n0 + p * 128 + srow) * ldB + k0 + lslot * 8,
                  lds + 12288 + buf * 8192 + p * 4096 + t * 8);
  };

  f32x4 acc[4][4];
#pragma unroll
  for (int m = 0; m < 4; ++m)
#pragma unroll
    for (int n = 0; n < 4; ++n) acc[m][n] = f32x4{0.f, 0.f, 0.f, 0.f};

  const int nt = Klen >> 5;
  STAGE(0, 0);
  STAGE(1, 32);
  asm volatile("s_waitcnt vmcnt(3)" ::: "memory");
  __builtin_amdgcn_s_barrier();

  int cur = 0;
  for (int it = 0; it < nt; ++it) {
    int pre = cur + 2; if (pre >= 3) pre -= 3;
    if (it + 2 < nt) STAGE(pre, (it + 2) << 5);
    const u16* Ab = lds + cur * 4096;
    const u16* Bb = lds + 12288 + cur * 8192;
    bf16x8 af[4], bfr[4];
#pragma unroll
    for (int m = 0; m < 4; ++m) {
      int row = wm * 64 + m * 16 + r;
      int ps = (g + (row >> 1)) & 3;
      af[m] = *(const bf16x8*)&Ab[row * 32 + ps * 8];
    }
#pragma unroll
    for (int n = 0; n < 4; ++n) {
      int row = wn * 64 + n * 16 + r;
      int ps = (g + (row >> 1)) & 3;
      bfr[n] = *(const bf16x8*)&Bb[row * 32 + ps * 8];
    }
#pragma unroll
    for (int m = 0; m < 4; ++m)
#pragma unroll
      for (int n = 0; n < 4; ++n)
        acc[m][n] = mfma16(af[m], bfr[n], acc[m][n]);
    if (it + 1 < nt) {
      if (it + 2 < nt) asm volatile("s_waitcnt vmcnt(3)" ::: "memory");
      else             asm volatile("s_waitcnt vmcnt(0)" ::: "memory");
      __builtin_amdgcn_s_barrier();
    }
    cur = cur + 1; if (cur >= 3) cur -= 3;
  }
  __builtin_amdgcn_s_barrier();

  if constexpr (OMODE == 0) {
    u16* myT = lds + wave * 2048;
    u16* Cg = (u16*)Cout + (size_t)(m0 + wm * 64) * ldC + n0 + wn * 64;
#pragma unroll
    for (int np = 0; np < 2; ++np) {
#pragma unroll
      for (int n2 = 0; n2 < 2; ++n2)
#pragma unroll
        for (int m = 0; m < 4; ++m)
#pragma unroll
          for (int rr = 0; rr < 4; ++rr) {
            int rl = m * 16 + 4 * g + rr;
            int cl = n2 * 16 + r;
            myT[rl * 32 + (((cl >> 3) ^ (rl & 3)) << 3) + (cl & 7)] =
                f2bf(acc[m][np * 2 + n2][rr] * cscale);
          }
#pragma unroll
      for (int i = 0; i < 4; ++i) {
        int idx = i * 64 + lane;
        int row = idx >> 2, c = idx & 3;
        bf16x8 v = *(const bf16x8*)&myT[row * 32 + ((c ^ (row & 3)) << 3)];
        *(bf16x8*)&Cg[(size_t)row * ldC + np * 32 + c * 8] = v;
      }
    }
  } else {
    float* myF = (float*)lds + wave * 2048;
    float bvn[4];
#pragma unroll
    for (int n = 0; n < 4; ++n) bvn[n] = bias[n0 + wn * 64 + n * 16 + r];
    float* Cg = (float*)Cout + (size_t)(m0 + wm * 64) * ldC + n0 + wn * 64;
#pragma unroll
    for (int np = 0; np < 2; ++np) {
#pragma unroll
      for (int n2 = 0; n2 < 2; ++n2)
#pragma unroll
        for (int m = 0; m < 4; ++m)
#pragma unroll
          for (int rr = 0; rr < 4; ++rr) {
            int rl = m * 16 + 4 * g + rr;
            int cl = n2 * 16 + r;
            myF[rl * 32 + ((((cl >> 2) ^ (rl & 7)) & 7) << 2) + (cl & 3)] =
                acc[m][np * 2 + n2][rr] + bvn[np * 2 + n2];
          }
#pragma unroll
      for (int i = 0; i < 8; ++i) {
        int idx = i * 64 + lane;
        int row = idx >> 3, c = idx & 7;
        float4 v = *(const float4*)&myF[row * 32 + (((c ^ (row & 7)) & 7) << 2)];
        *(float4*)&Cg[(size_t)row * ldC + np * 32 + c * 4] = v;
      }
    }
  }
}

// ------------- NEW: 128x128 BK=64 GEMM — half the sync epochs, 2 WGs/CU -------------
// 256 thr = 4 waves (2x2), per-wave 64x64 (acc[4][4]). LDS 64 KB: 2 bufs of (A 16KB + B 16KB).
// Per K-epoch: 8 gloads staged, 16 ds_read_b128 + 32 MFMA per wave, ONE vmcnt(0)+barrier
// (16 epochs for K=1024 vs 32 in all prior structures). The drain is issued ~600 cyc after
// the stage (covered for L2-resident operands). Slot rotation phys=(slot+row)&7 -> reads
// are 2-way bank aliased (free, m136); inverse rotation on global source (rule #21).
template<int OMODE>   // 0 = bf16*cscale, 1 = fp32 + bias
__global__ __launch_bounds__(256, 2)
void qgemm64_kernel(const u16* __restrict__ A, const u16* __restrict__ Bt,
                    void* __restrict__ Cout, const float* __restrict__ bias,
                    float cscale, int ldA, int ldB, int ldC, int Klen) {
  __shared__ __align__(16) u16 lds[32768];   // 64 KB
  const int t = threadIdx.x;
  const int lane = t & 63, wave = t >> 6;
  const int g = lane >> 4, r = lane & 15;
  const int wm = wave >> 1, wn = wave & 1;           // 2M x 2N
  const int id = blockIdx.y * gridDim.x + blockIdx.x;  // gx=8, gy=128 -> 1024 WGs
  const int cpx = (gridDim.x * gridDim.y) >> 3;
  const int s = (id & 7) * cpx + (id >> 3);
  const int bx = s & 7, by = s >> 3;
  const int m0 = by * 128, n0 = bx * 128;

  auto STAGE = [&](int buf, int k0) {
#pragma unroll
    for (int j = 0; j < 4; ++j) {                    // A: 128 rows x 8 slots = 1024 units
      int u = j * 256 + t;
      int row = u >> 3, psl = u & 7;
      int sl = (psl + 8 - (row & 7)) & 7;            // inverse rotation on global source
      gload_lds16(A + (size_t)(m0 + row) * ldA + k0 + sl * 8,
                  lds + buf * 16384 + u * 8);
    }
#pragma unroll
    for (int j = 0; j < 4; ++j) {                    // B likewise
      int u = j * 256 + t;
      int row = u >> 3, psl = u & 7;
      int sl = (psl + 8 - (row & 7)) & 7;
      gload_lds16(Bt + (size_t)(n0 + row) * ldB + k0 + sl * 8,
                  lds + buf * 16384 + 8192 + u * 8);
    }
  };

  f32x4 acc[4][4];
#pragma unroll
  for (int m = 0; m < 4; ++m)
#pragma unroll
    for (int n = 0; n < 4; ++n) acc[m][n] = f32x4{0.f, 0.f, 0.f, 0.f};

  const int nt = Klen >> 6;   // 16
  STAGE(0, 0);
  asm volatile("s_waitcnt vmcnt(0)" ::: "memory");
  __builtin_amdgcn_s_barrier();

  int cur = 0;
  for (int it = 0; it < nt; ++it) {
    if (it + 1 < nt) STAGE(cur ^ 1, (it + 1) << 6);
    const u16* Ab = lds + cur * 16384;
    const u16* Bb = Ab + 8192;
    bf16x8 af[4][2], bfr[4][2];
#pragma unroll
    for (int m = 0; m < 4; ++m) {
      int row = wm * 64 + m * 16 + r;
      af[m][0] = *(const bf16x8*)&Ab[row * 64 + (((g + row) & 7) << 3)];
      af[m][1] = *(const bf16x8*)&Ab[row * 64 + (((4 + g + row) & 7) << 3)];
    }
#pragma unroll
    for (int n = 0; n < 4; ++n) {
      int row = wn * 64 + n * 16 + r;
      bfr[n][0] = *(const bf16x8*)&Bb[row * 64 + (((g + row) & 7) << 3)];
      bfr[n][1] = *(const bf16x8*)&Bb[row * 64 + (((4 + g + row) & 7) << 3)];
    }
#pragma unroll
    for (int m = 0; m < 4; ++m)
#pragma unroll
      for (int n = 0; n < 4; ++n) {
        acc[m][n] = mfma16(af[m][0], bfr[n][0], acc[m][n]);
        acc[m][n] = mfma16(af[m][1], bfr[n][1], acc[m][n]);
      }
    if (it + 1 < nt) {
      asm volatile("s_waitcnt vmcnt(0)" ::: "memory");
      __builtin_amdgcn_s_barrier();
    }
    cur ^= 1;
  }
  __builtin_amdgcn_s_barrier();   // all LDS reads done before epilogue overwrites

  // epilogue: per-wave 64x64; C row = m0+wm*64+m*16+4g+rr, col = n0+wn*64+n*16+r
  if constexpr (OMODE == 0) {
    u16* myT = lds + wave * 4096;   // 8 KB/wave
    u16* Cg = (u16*)Cout + (size_t)(m0 + wm * 64) * ldC + n0 + wn * 64;
#pragma unroll
    for (int m = 0; m < 4; ++m)
#pragma unroll
      for (int n = 0; n < 4; ++n)
#pragma unroll
        for (int rr = 0; rr < 4; ++rr) {
          int rl = m * 16 + 4 * g + rr;
          int cl = n * 16 + r;
          myT[rl * 64 + (((cl >> 3) ^ (rl & 7)) << 3) + (cl & 7)] = f2bf(acc[m][n][rr] * cscale);
        }
#pragma unroll
    for (int i = 0; i < 8; ++i) {
      int idx = i * 64 + lane;
      int row = idx >> 3, c8 = idx & 7;
      bf16x8 v = *(const bf16x8*)&myT[row * 64 + ((c8 ^ (row & 7)) << 3)];
      *(bf16x8*)&Cg[(size_t)row * ldC + c8 * 8] = v;
    }
  } else {
    float* myF = (float*)lds + wave * 2048;   // 8 KB/wave
    float bvn[4];
#pragma unroll
    for (int n = 0; n < 4; ++n) bvn[n] = bias[n0 + wn * 64 + n * 16 + r];
    float* Cg = (float*)Cout + (size_t)(m0 + wm * 64) * ldC + n0 + wn * 64;
#pragma unroll
    for (int np = 0; np < 2; ++np) {
#pragma unroll
      for (int n2 = 0; n2 < 2; ++n2)
#pragma unroll
        for (int m = 0; m < 4; ++m)
#pragma unroll
          for (int rr = 0; rr < 4; ++rr) {
            int rl = m * 16 + 4 * g + rr;
            int cl = n2 * 16 + r;
            myF[rl * 32 + ((((cl >> 2) ^ (rl & 7)) & 7) << 2) + (cl & 3)] =
                acc[m][np * 2 + n2][rr] + bvn[np * 2 + n2];
          }
#pragma unroll
      for (int i = 0; i < 8; ++i) {
        int idx = i * 64 + lane;
        int row = idx >> 3, c = idx & 7;
        float4 v = *(const float4*)&myF[row * 32 + (((c ^ (row & 7)) & 7) << 2)];
        *(float4*)&Cg[(size_t)row * ldC + np * 32 + c * 4] = v;
      }
    }
  }
}

// ------------- fused attention (frozen from R14) -------------
__global__ __launch_bounds__(256, 3)
void attn_kernel(const u16* __restrict__ Q, const u16* __restrict__ Kl,
                 const u16* __restrict__ VT, u16* __restrict__ Out) {
  __shared__ __align__(16) u16 sm[24576];   // 48 KB
  const int t = threadIdx.x, lane = t & 63, w = t >> 6;
  const int g = lane >> 4, r = lane & 15;
  const int id = (blockIdx.y << 6) | blockIdx.x;
  const int s = (id & 7) * (gridDim.y << 3) + (id >> 3);
  const int b = blockIdx.z, h = s >> 6, n0 = (s & 63) * 64;
  const u16* Kb = Kl + (size_t)b * 262144 + h * 64;
  const u16* Vb = VT + (size_t)b * 262144 + (size_t)(h * 64) * 256;
  u16* vbase = sm + 16384;

  auto stage_slice = [&](int sl64, int buf) {
#pragma unroll
    for (int i = 0; i < 2; ++i) {
      int u = i * 256 + t;
      int d = u >> 3, ps = u & 7;
      gload_lds16(Vb + (size_t)d * 256 + sl64 * 64 + (ps ^ (d & 7)) * 8,
                  vbase + buf * 4096 + i * 2048 + t * 8);
    }
  };

#pragma unroll
  for (int p = 0; p < 8; ++p) {
    int row = p * 32 + (t >> 3);
    int ls = ((t & 7) + 8 - (row & 7)) & 7;
    gload_lds16(Kb + (size_t)row * 1024 + ls * 8, sm + p * 2048 + w * 512);
  }
  stage_slice(0, 0);
  stage_slice(1, 1);
  const int qrow = n0 + w * 16 + r;
  const u16* Qp = Q + ((size_t)(b * 4096 + qrow)) * 1024 + h * 64 + g * 8;
  bf16x8 aq0 = *(const bf16x8*)Qp;
  bf16x8 aq1 = *(const bf16x8*)(Qp + 32);
  asm volatile("s_waitcnt vmcnt(4)" ::: "memory");
  __builtin_amdgcn_s_barrier();

  f32x4 dotv[16];
  __builtin_amdgcn_s_setprio(1);
#pragma unroll
  for (int kf = 0; kf < 16; ++kf) {
    int row = kf * 16 + r;
    bf16x8 kb0 = *(const bf16x8*)&sm[row * 64 + ((g + row) & 7) * 8];
    bf16x8 kb1 = *(const bf16x8*)&sm[row * 64 + ((4 + g + row) & 7) * 8];
    f32x4 d = f32x4{0.f, 0.f, 0.f, 0.f};
    d = mfma16(kb0, aq0, d);
    d = mfma16(kb1, aq1, d);
    dotv[kf] = d;
  }
  __builtin_amdgcn_s_setprio(0);
  asm volatile("s_waitcnt vmcnt(2)" ::: "memory");
  __builtin_amdgcn_s_barrier();

  float mx = -3.4e38f;
#pragma unroll
  for (int kf = 0; kf < 16; ++kf)
    mx = fmaxf(mx, fmaxf(fmaxf(dotv[kf][0], dotv[kf][1]), fmaxf(dotv[kf][2], dotv[kf][3])));
  mx = fmaxf(mx, __shfl_xor(mx, 16, 64));
  mx = fmaxf(mx, __shfl_xor(mx, 32, 64));
  float ssum = 0.f;
#pragma unroll
  for (int kf = 0; kf < 16; ++kf)
#pragma unroll
    for (int j = 0; j < 4; ++j) {
      float p = __builtin_amdgcn_exp2f(dotv[kf][j] - mx);
      dotv[kf][j] = p;
      ssum += p;
    }
  ssum += __shfl_xor(ssum, 16, 64);
  ssum += __shfl_xor(ssum, 32, 64);
  const float inv = 1.f / ssum;
  float invv[4];
#pragma unroll
  for (int rr = 0; rr < 4; ++rr) invv[rr] = __shfl(inv, 4 * g + rr, 64);

  const int q16 = w * 16 + r;
  const int qx = (q16 & 7) << 3;
#pragma unroll
  for (int kf = 0; kf < 16; ++kf) {
    uint2 val;
    val.x = pk2(dotv[kf][0], dotv[kf][1]);
    val.y = pk2(dotv[kf][2], dotv[kf][3]);
    *(uint2*)&sm[(q16 * 256 + kf * 16 + 4 * g) ^ qx] = val;
  }

  f32x4 oacc[4];
#pragma unroll
  for (int df = 0; df < 4; ++df) oacc[df] = f32x4{0.f, 0.f, 0.f, 0.f};
#pragma unroll
  for (int ph = 0; ph < 4; ++ph) {
    const u16* vb = vbase + (ph & 1) * 4096;
    __builtin_amdgcn_s_setprio(1);
#pragma unroll
    for (int kk2 = 0; kk2 < 2; ++kk2) {
      int kk = ph * 2 + kk2;
      bf16x8 ap = *(const bf16x8*)&sm[(q16 * 256 + kk * 32 + g * 8) ^ qx];
#pragma unroll
      for (int df = 0; df < 4; ++df) {
        int d = df * 16 + r;
        bf16x8 bv = *(const bf16x8*)&vb[d * 64 + ((kk2 * 4 + g) ^ (d & 7)) * 8];
        oacc[df] = mfma16(ap, bv, oacc[df]);
      }
    }
    __builtin_amdgcn_s_setprio(0);
    if (ph < 3) {
      asm volatile("s_waitcnt vmcnt(0)" ::: "memory");
      __builtin_amdgcn_s_barrier();
      if (ph < 2) stage_slice(ph + 2, ph & 1);
    }
  }

  u16* myO = sm + w * 4096;
#pragma unroll
  for (int df = 0; df < 4; ++df)
#pragma unroll
    for (int rr = 0; rr < 4; ++rr) {
      int row = 4 * g + rr;
      int col = df * 16 + r;
      myO[row * 64 + (((col >> 3) ^ (row & 7)) << 3) + (col & 7)] = f2bf(oacc[df][rr] * invv[rr]);
    }
#pragma unroll
  for (int i = 0; i < 2; ++i) {
    int idx = i * 64 + lane;
    int row = idx >> 3, c8 = idx & 7;
    bf16x8 v = *(const bf16x8*)&myO[row * 64 + ((c8 ^ (row & 7)) << 3)];
    *(bf16x8*)&Out[((size_t)(b * 4096 + n0 + w * 16 + row)) * 1024 + h * 64 + c8 * 8] = v;
  }
}

extern "C" void kernel_launch(void* const* d_in, const int* in_sizes, int n_in,
                              void* d_out, int out_size, void* d_ws, size_t ws_size,
                              hipStream_t stream) {
  const float* x  = (const float*)d_in[0];
  const float* Wq = (const float*)d_in[1];
  const float* Wk = (const float*)d_in[2];
  const float* Wv = (const float*)d_in[3];
  const float* pk = (const float*)d_in[4];
  const float* pv = (const float*)d_in[5];
  const float* Wo = (const float*)d_in[6];
  const float* bo = (const float*)d_in[7];

  u16* ws = (u16*)d_ws;
  u16* xbf   = ws;                   // [4][4096][1024]
  u16* xT    = xbf + 16777216;       // [4][1024][4096] == xT_flat [4096][4096]
  u16* wqb   = xT + 16777216;        // [1024][1024]
  u16* wkb   = wqb + 1048576;
  u16* wvb   = wkb + 1048576;
  u16* wob   = wvb + 1048576;
  u16* projT = wob + 1048576;        // [512][4096]
  u16* Qb    = projT + 2097152;      // [16384][1024]; holds xp bf16 partials first
  u16* xp    = Qb + 16777216;        // [512][4096] bf16
  u16* klow  = xp + 2097152;         // [4][256][1024]
  u16* vT    = klow + 1048576;       // [4][1024][256]
  u16* aout  = xbf;                  // reuse after Q GEMM
  u16* xp_part = Qb;                 // [4 z][512][4096] bf16 (in Qb region)

  // 1) x: convert + row-major bf16 + transpose (one read of x)
  cvt_xpose_kernel<<<dim3(16, 64, 4), 256, 0, stream>>>(x, xbf, xT, 4096, 1024,
                                                        4194304, 4194304, 4194304);
  // 2) weights + proj transposes merged
  cvt_misc_kernel<<<dim3(1024, 6), 256, 0, stream>>>(Wq, Wk, Wv, Wo, wqb, wkb, wvb, wob,
                                                     pk, pv, projT);
  // 3) xp partials (bf16): ONE GEMM M=512, N=4096, K=4096, split-K x4
  gemm_bt_kernel<4><<<dim3(32, 4, 4), 256, 0, stream>>>(
      projT, xT, nullptr, (void*)xp_part, nullptr, nullptr, 1.f,
      4096, 4096, 4096, 1024, 0, 0, 2097152, 1, 1024, 1024);
  // 4) reduce bf16 partials -> xp bf16 [512][4096]
  reduce4_kernel<<<1024, 256, 0, stream>>>(xp_part, xp);
  // 5) kv: z = b'*2 + half; K half -> klow row-major, V half -> vT transposed
  gemm_bt_kernel<3><<<dim3(8, 2, 8), 256, 0, stream>>>(
      xp, wkb, wvb, (void*)klow, vT, nullptr, 1.f,
      4096, 1024, 1024, 1024, 1048576, 0, 262144, 2, 1024, 0);
  // 6) Q = (x @ Wq^T) * QSCALE — 3-deep-ring 128x256 kernel (control)
  qgemm128_kernel<0><<<dim3(4, 128), 512, 0, stream>>>(
      xbf, wqb, (void*)Qb, nullptr, QSCALE, 1024, 1024, 1024, 1024);
  // 7) attention
  attn_kernel<<<dim3(64, 16, 4), 256, 0, stream>>>(Qb, klow, vT, aout);
  // 8) final = attn_out @ Wo^T + bo -> fp32 d_out — NEW BK=64 kernel (A/B arm)
  qgemm64_kernel<1><<<dim3(8, 128), 256, 0, stream>>>(
      aout, wob, d_out, bo, 1.f, 1024, 1024, 1024, 1024);
}

// Round 18
// 201.673 us; speedup vs baseline: 1.0763x; 1.0045x over previous
//
#include <hip/hip_runtime.h>
#include <hip/hip_bf16.h>
#include <stdint.h>

typedef unsigned short u16;
typedef __attribute__((ext_vector_type(8))) short bf16x8;   // 8 bf16 = 4 VGPRs
typedef __attribute__((ext_vector_type(4))) float f32x4;

#define DEV __device__ __forceinline__

DEV u16 f2bf(float f) {
  union { float f; unsigned u; } v; v.f = f;
  unsigned r = (v.u + 0x7fffu + ((v.u >> 16) & 1u)) >> 16;   // RNE
  return (u16)r;
}

DEV float bf2f(u16 h) {
  union { unsigned u; float f; } v; v.u = ((unsigned)h) << 16;
  return v.f;
}

// packed 2x f32 -> 2x bf16 (v_cvt_pk_bf16_f32), RNE
DEV unsigned pk2(float lo, float hi) {
  union { __hip_bfloat162 h; unsigned u; } c;
  c.h = __float22bfloat162_rn(make_float2(lo, hi));
  return c.u;
}

DEV f32x4 mfma16(bf16x8 a, bf16x8 b, f32x4 c) {
  return __builtin_amdgcn_mfma_f32_16x16x32_bf16(a, b, c, 0, 0, 0);
}

DEV void gload_lds16(const u16* g, u16* l) {
  __builtin_amdgcn_global_load_lds((const __attribute__((address_space(1))) void*)g,
                                   (__attribute__((address_space(3))) void*)l, 16, 0, 0);
}

// softmax logit pre-scale folded into Q: dh^-0.5 (=1/8) * log2(e), so exp = exp2
#define QSCALE 0.18033688011112042f

// ---------------- fused fp32 -> bf16 convert (+ optional row-major copy) + transpose ----------------
__global__ void cvt_xpose_kernel(const float* __restrict__ src, u16* __restrict__ dst_rm,
                                 u16* __restrict__ dst_tp, int R, int C,
                                 long zS, long zRM, long zTP) {
  __shared__ u16 tile[64][72];
  src += (size_t)blockIdx.z * zS;
  dst_tp += (size_t)blockIdx.z * zTP;
  int r0 = blockIdx.y * 64, c0 = blockIdx.x * 64;
  int tr = threadIdx.x >> 2, tc = (threadIdx.x & 3) * 16;
  const float* s = src + (size_t)(r0 + tr) * C + c0 + tc;
  u16 loc[16];
#pragma unroll
  for (int q = 0; q < 4; ++q) {
    float4 v = ((const float4*)s)[q];
    loc[q * 4 + 0] = f2bf(v.x); loc[q * 4 + 1] = f2bf(v.y);
    loc[q * 4 + 2] = f2bf(v.z); loc[q * 4 + 3] = f2bf(v.w);
  }
#pragma unroll
  for (int i = 0; i < 16; ++i) tile[tr][tc + i] = loc[i];
  if (dst_rm) {
    u16* d = dst_rm + (size_t)blockIdx.z * zRM + (size_t)(r0 + tr) * C + c0 + tc;
    *(bf16x8*)d = *(const bf16x8*)&loc[0];
    *(bf16x8*)(d + 8) = *(const bf16x8*)&loc[8];
  }
  __syncthreads();
  u16 tmp[16];
#pragma unroll
  for (int i = 0; i < 16; ++i) tmp[i] = tile[tc + i][tr];
  u16* d = dst_tp + (size_t)(c0 + tr) * R + r0 + tc;
  *(bf16x8*)d = *(const bf16x8*)&tmp[0];
  *(bf16x8*)(d + 8) = *(const bf16x8*)&tmp[8];
}

// ---------------- merged: 4 weight converts (y 0-3) + proj_k/proj_v transposes (y 4-5) ----------------
__global__ void cvt_misc_kernel(const float* __restrict__ s0, const float* __restrict__ s1,
                                const float* __restrict__ s2, const float* __restrict__ s3,
                                u16* __restrict__ d0, u16* __restrict__ d1,
                                u16* __restrict__ d2, u16* __restrict__ d3,
                                const float* __restrict__ pk, const float* __restrict__ pv,
                                u16* __restrict__ projT) {
  __shared__ u16 tile[64][72];
  const int y = blockIdx.y;
  if (y < 4) {
    const float* s; u16* d;
    switch (y) {
      case 0: s = s0; d = d0; break;
      case 1: s = s1; d = d1; break;
      case 2: s = s2; d = d2; break;
      default: s = s3; d = d3; break;
    }
    int i = blockIdx.x * 256 + threadIdx.x;
    float4 v = ((const float4*)s)[i];
    ushort4 o; o.x = f2bf(v.x); o.y = f2bf(v.y); o.z = f2bf(v.z); o.w = f2bf(v.w);
    ((ushort4*)d)[i] = o;
    return;
  }
  if (blockIdx.x >= 256) return;
  const float* src = (y == 4) ? pk : pv;
  u16* dst = projT + (size_t)(y - 4) * 1048576;
  int r0 = (blockIdx.x >> 2) * 64, c0 = (blockIdx.x & 3) * 64;
  int tr = threadIdx.x >> 2, tc = (threadIdx.x & 3) * 16;
  const float* s = src + (size_t)(r0 + tr) * 256 + c0 + tc;
  u16 loc[16];
#pragma unroll
  for (int q = 0; q < 4; ++q) {
    float4 v = ((const float4*)s)[q];
    loc[q * 4 + 0] = f2bf(v.x); loc[q * 4 + 1] = f2bf(v.y);
    loc[q * 4 + 2] = f2bf(v.z); loc[q * 4 + 3] = f2bf(v.w);
  }
#pragma unroll
  for (int i = 0; i < 16; ++i) tile[tr][tc + i] = loc[i];
  __syncthreads();
  u16 tmp[16];
#pragma unroll
  for (int i = 0; i < 16; ++i) tmp[i] = tile[tc + i][tr];
  u16* d = dst + (size_t)(c0 + tr) * 4096 + r0 + tc;
  *(bf16x8*)d = *(const bf16x8*)&tmp[0];
  *(bf16x8*)(d + 8) = *(const bf16x8*)&tmp[8];
}

// ---------------- split-K reduce: 4x bf16 partials -> bf16, fp32 accum ----------------
__global__ void reduce4_kernel(const u16* __restrict__ part, u16* __restrict__ out) {
  int i = blockIdx.x * 256 + threadIdx.x;   // bf16x8 unit; total 262144 units
  bf16x8 a = ((const bf16x8*)part)[i];
  bf16x8 b = ((const bf16x8*)part)[i + 262144];
  bf16x8 c = ((const bf16x8*)part)[i + 524288];
  bf16x8 d = ((const bf16x8*)part)[i + 786432];
  u16 o[8];
#pragma unroll
  for (int j = 0; j < 8; ++j)
    o[j] = f2bf(bf2f((u16)a[j]) + bf2f((u16)b[j]) + bf2f((u16)c[j]) + bf2f((u16)d[j]));
  ((bf16x8*)out)[i] = *(const bf16x8*)&o[0];
}

// ------------- 128x128 2-phase GEMM (xp split-K and kv) -------------
template<int OMODE>
__global__ __launch_bounds__(256, 4)
void gemm_bt_kernel(const u16* __restrict__ A, const u16* __restrict__ Bt,
                    const u16* __restrict__ Bt2, void* __restrict__ Cout,
                    u16* __restrict__ CoutT, const float* __restrict__ bias, float cscale,
                    int ldA, int ldB, int ldC, int Klen,
                    long zA, long zB, long zC, int bMod, long kChunkA, long kChunkB) {
  __shared__ __align__(16) u16 smA[2][128 * 32];
  __shared__ __align__(16) u16 smB[2][128 * 32];
  const int t = threadIdx.x;
  const int lane = t & 63, wave = t >> 6;
  const int wm = wave & 1, wn = wave >> 1;
  const int g = lane >> 4, r = lane & 15;
  const int id = blockIdx.y * gridDim.x + blockIdx.x;
  const int cpx = (gridDim.x * gridDim.y) >> 3;
  const int s = (id & 7) * cpx + (id >> 3);
  const int bx = s % gridDim.x, by = s / gridDim.x;
  const int z = blockIdx.z;
  const int b = z % bMod, kc = z / bMod;
  const u16* Ab = A + (size_t)b * zA + (size_t)kc * kChunkA;
  const u16* Bbase = (Bt2 && (b & 1)) ? Bt2 : Bt;
  const u16* Bb = Bbase + (size_t)b * zB + (size_t)kc * kChunkB;
  const int m0 = by * 128, n0 = bx * 128;
  const int srow = t >> 2;
  const int lslot = ((t & 3) + 4 - ((srow >> 1) & 3)) & 3;

  f32x4 acc[4][4];
#pragma unroll
  for (int m = 0; m < 4; ++m)
#pragma unroll
    for (int n = 0; n < 4; ++n) acc[m][n] = f32x4{0.f, 0.f, 0.f, 0.f};

  auto STAGE = [&](int buf, int k0) {
#pragma unroll
    for (int p = 0; p < 2; ++p) {
      int row = p * 64 + srow;
      gload_lds16(Ab + (size_t)(m0 + row) * ldA + k0 + lslot * 8, &smA[buf][p * 2048 + wave * 512]);
      gload_lds16(Bb + (size_t)(n0 + row) * ldB + k0 + lslot * 8, &smB[buf][p * 2048 + wave * 512]);
    }
  };

  const int nt = Klen >> 5;
  STAGE(0, 0);
  __syncthreads();
  int cur = 0;
  for (int it = 0; it < nt; ++it) {
    if (it + 1 < nt) STAGE(cur ^ 1, (it + 1) << 5);
    bf16x8 af[4], bfr[4];
#pragma unroll
    for (int m = 0; m < 4; ++m) {
      int row = wm * 64 + m * 16 + r;
      int ps = (g + (row >> 1)) & 3;
      af[m] = *(const bf16x8*)&smA[cur][row * 32 + ps * 8];
    }
#pragma unroll
    for (int n = 0; n < 4; ++n) {
      int row = wn * 64 + n * 16 + r;
      int ps = (g + (row >> 1)) & 3;
      bfr[n] = *(const bf16x8*)&smB[cur][row * 32 + ps * 8];
    }
#pragma unroll
    for (int m = 0; m < 4; ++m)
#pragma unroll
      for (int n = 0; n < 4; ++n)
        acc[m][n] = mfma16(af[m], bfr[n], acc[m][n]);
    __syncthreads();
    cur ^= 1;
  }

  if constexpr (OMODE == 4) {
    u16* myT = (u16*)&smA[0][0] + wave * 4096;
    u16* Cg = (u16*)Cout + (size_t)z * zC + (size_t)(m0 + wm * 64) * ldC + n0 + wn * 64;
#pragma unroll
    for (int m = 0; m < 4; ++m)
#pragma unroll
      for (int n = 0; n < 4; ++n)
#pragma unroll
        for (int rr = 0; rr < 4; ++rr) {
          int rl = m * 16 + 4 * g + rr;
          int cl = n * 16 + r;
          myT[rl * 64 + (((cl >> 3) ^ (rl & 7)) << 3) + (cl & 7)] = f2bf(acc[m][n][rr]);
        }
#pragma unroll
    for (int i = 0; i < 8; ++i) {
      int idx = i * 64 + lane;
      int row = idx >> 3, c8 = idx & 7;
      bf16x8 v = *(const bf16x8*)&myT[row * 64 + ((c8 ^ (row & 7)) << 3)];
      *(bf16x8*)&Cg[(size_t)row * ldC + c8 * 8] = v;
    }
  } else {  // OMODE == 3
    if ((z & 1) == 0) {
      u16* C = (u16*)Cout + (size_t)(z >> 1) * zC;
#pragma unroll
      for (int n = 0; n < 4; ++n) {
        int col = n0 + wn * 64 + n * 16 + r;
#pragma unroll
        for (int m = 0; m < 4; ++m) {
          int rowb = m0 + wm * 64 + m * 16 + 4 * g;
#pragma unroll
          for (int rr = 0; rr < 4; ++rr)
            C[(size_t)(rowb + rr) * ldC + col] = f2bf(acc[m][n][rr]);
        }
      }
    } else {
      u16* C = CoutT + (size_t)(z >> 1) * zC;
#pragma unroll
      for (int n = 0; n < 4; ++n) {
        int col = n0 + wn * 64 + n * 16 + r;
#pragma unroll
        for (int m = 0; m < 4; ++m) {
          int rowb = m0 + wm * 64 + m * 16 + 4 * g;
          ushort4 o;
          o.x = f2bf(acc[m][n][0]); o.y = f2bf(acc[m][n][1]);
          o.z = f2bf(acc[m][n][2]); o.w = f2bf(acc[m][n][3]);
          *(ushort4*)&C[(size_t)col * 256 + rowb] = o;
        }
      }
    }
  }
}

// ------------- 128x128 BK=64 GEMM — half the sync epochs, 2 WGs/CU (both big GEMMs) -------------
// 256 thr = 4 waves (2x2), per-wave 64x64 (acc[4][4]). LDS 64 KB: 2 bufs of (A 16KB + B 16KB).
// Per K-epoch: 8 gloads staged, 16 ds_read_b128 + 32 MFMA per wave, ONE vmcnt(0)+barrier
// (16 epochs for K=1024 vs 32 in prior structures — measured −2us vs qgemm128 in R17 A/B).
// Slot rotation phys=(slot+row)&7 (2-way bank alias = free); inverse on global source.
template<int OMODE>   // 0 = bf16*cscale, 1 = fp32 + bias
__global__ __launch_bounds__(256, 2)
void qgemm64_kernel(const u16* __restrict__ A, const u16* __restrict__ Bt,
                    void* __restrict__ Cout, const float* __restrict__ bias,
                    float cscale, int ldA, int ldB, int ldC, int Klen) {
  __shared__ __align__(16) u16 lds[32768];   // 64 KB
  const int t = threadIdx.x;
  const int lane = t & 63, wave = t >> 6;
  const int g = lane >> 4, r = lane & 15;
  const int wm = wave >> 1, wn = wave & 1;           // 2M x 2N
  const int id = blockIdx.y * gridDim.x + blockIdx.x;  // gx=8, gy=128 -> 1024 WGs
  const int cpx = (gridDim.x * gridDim.y) >> 3;
  const int s = (id & 7) * cpx + (id >> 3);
  const int bx = s & 7, by = s >> 3;
  const int m0 = by * 128, n0 = bx * 128;

  auto STAGE = [&](int buf, int k0) {
#pragma unroll
    for (int j = 0; j < 4; ++j) {                    // A: 128 rows x 8 slots = 1024 units
      int u = j * 256 + t;
      int row = u >> 3, psl = u & 7;
      int sl = (psl + 8 - (row & 7)) & 7;            // inverse rotation on global source
      gload_lds16(A + (size_t)(m0 + row) * ldA + k0 + sl * 8,
                  lds + buf * 16384 + u * 8);
    }
#pragma unroll
    for (int j = 0; j < 4; ++j) {                    // B likewise
      int u = j * 256 + t;
      int row = u >> 3, psl = u & 7;
      int sl = (psl + 8 - (row & 7)) & 7;
      gload_lds16(Bt + (size_t)(n0 + row) * ldB + k0 + sl * 8,
                  lds + buf * 16384 + 8192 + u * 8);
    }
  };

  f32x4 acc[4][4];
#pragma unroll
  for (int m = 0; m < 4; ++m)
#pragma unroll
    for (int n = 0; n < 4; ++n) acc[m][n] = f32x4{0.f, 0.f, 0.f, 0.f};

  const int nt = Klen >> 6;   // 16
  STAGE(0, 0);
  asm volatile("s_waitcnt vmcnt(0)" ::: "memory");
  __builtin_amdgcn_s_barrier();

  int cur = 0;
  for (int it = 0; it < nt; ++it) {
    if (it + 1 < nt) STAGE(cur ^ 1, (it + 1) << 6);
    const u16* Ab = lds + cur * 16384;
    const u16* Bb = Ab + 8192;
    bf16x8 af[4][2], bfr[4][2];
#pragma unroll
    for (int m = 0; m < 4; ++m) {
      int row = wm * 64 + m * 16 + r;
      af[m][0] = *(const bf16x8*)&Ab[row * 64 + (((g + row) & 7) << 3)];
      af[m][1] = *(const bf16x8*)&Ab[row * 64 + (((4 + g + row) & 7) << 3)];
    }
#pragma unroll
    for (int n = 0; n < 4; ++n) {
      int row = wn * 64 + n * 16 + r;
      bfr[n][0] = *(const bf16x8*)&Bb[row * 64 + (((g + row) & 7) << 3)];
      bfr[n][1] = *(const bf16x8*)&Bb[row * 64 + (((4 + g + row) & 7) << 3)];
    }
#pragma unroll
    for (int m = 0; m < 4; ++m)
#pragma unroll
      for (int n = 0; n < 4; ++n) {
        acc[m][n] = mfma16(af[m][0], bfr[n][0], acc[m][n]);
        acc[m][n] = mfma16(af[m][1], bfr[n][1], acc[m][n]);
      }
    if (it + 1 < nt) {
      asm volatile("s_waitcnt vmcnt(0)" ::: "memory");
      __builtin_amdgcn_s_barrier();
    }
    cur ^= 1;
  }
  __builtin_amdgcn_s_barrier();   // all LDS reads done before epilogue overwrites

  // epilogue: per-wave 64x64; C row = m0+wm*64+m*16+4g+rr, col = n0+wn*64+n*16+r
  if constexpr (OMODE == 0) {
    u16* myT = lds + wave * 4096;   // 8 KB/wave
    u16* Cg = (u16*)Cout + (size_t)(m0 + wm * 64) * ldC + n0 + wn * 64;
#pragma unroll
    for (int m = 0; m < 4; ++m)
#pragma unroll
      for (int n = 0; n < 4; ++n)
#pragma unroll
        for (int rr = 0; rr < 4; ++rr) {
          int rl = m * 16 + 4 * g + rr;
          int cl = n * 16 + r;
          myT[rl * 64 + (((cl >> 3) ^ (rl & 7)) << 3) + (cl & 7)] = f2bf(acc[m][n][rr] * cscale);
        }
#pragma unroll
    for (int i = 0; i < 8; ++i) {
      int idx = i * 64 + lane;
      int row = idx >> 3, c8 = idx & 7;
      bf16x8 v = *(const bf16x8*)&myT[row * 64 + ((c8 ^ (row & 7)) << 3)];
      *(bf16x8*)&Cg[(size_t)row * ldC + c8 * 8] = v;
    }
  } else {
    float* myF = (float*)lds + wave * 2048;   // 8 KB/wave
    float bvn[4];
#pragma unroll
    for (int n = 0; n < 4; ++n) bvn[n] = bias[n0 + wn * 64 + n * 16 + r];
    float* Cg = (float*)Cout + (size_t)(m0 + wm * 64) * ldC + n0 + wn * 64;
#pragma unroll
    for (int np = 0; np < 2; ++np) {
#pragma unroll
      for (int n2 = 0; n2 < 2; ++n2)
#pragma unroll
        for (int m = 0; m < 4; ++m)
#pragma unroll
          for (int rr = 0; rr < 4; ++rr) {
            int rl = m * 16 + 4 * g + rr;
            int cl = n2 * 16 + r;
            myF[rl * 32 + ((((cl >> 2) ^ (rl & 7)) & 7) << 2) + (cl & 3)] =
                acc[m][np * 2 + n2][rr] + bvn[np * 2 + n2];
          }
#pragma unroll
      for (int i = 0; i < 8; ++i) {
        int idx = i * 64 + lane;
        int row = idx >> 3, c = idx & 7;
        float4 v = *(const float4*)&myF[row * 32 + (((c ^ (row & 7)) & 7) << 2)];
        *(float4*)&Cg[(size_t)row * ldC + np * 32 + c * 4] = v;
      }
    }
  }
}

// ------------- fused attention (frozen from R14) -------------
__global__ __launch_bounds__(256, 3)
void attn_kernel(const u16* __restrict__ Q, const u16* __restrict__ Kl,
                 const u16* __restrict__ VT, u16* __restrict__ Out) {
  __shared__ __align__(16) u16 sm[24576];   // 48 KB
  const int t = threadIdx.x, lane = t & 63, w = t >> 6;
  const int g = lane >> 4, r = lane & 15;
  const int id = (blockIdx.y << 6) | blockIdx.x;
  const int s = (id & 7) * (gridDim.y << 3) + (id >> 3);
  const int b = blockIdx.z, h = s >> 6, n0 = (s & 63) * 64;
  const u16* Kb = Kl + (size_t)b * 262144 + h * 64;
  const u16* Vb = VT + (size_t)b * 262144 + (size_t)(h * 64) * 256;
  u16* vbase = sm + 16384;

  auto stage_slice = [&](int sl64, int buf) {
#pragma unroll
    for (int i = 0; i < 2; ++i) {
      int u = i * 256 + t;
      int d = u >> 3, ps = u & 7;
      gload_lds16(Vb + (size_t)d * 256 + sl64 * 64 + (ps ^ (d & 7)) * 8,
                  vbase + buf * 4096 + i * 2048 + t * 8);
    }
  };

#pragma unroll
  for (int p = 0; p < 8; ++p) {
    int row = p * 32 + (t >> 3);
    int ls = ((t & 7) + 8 - (row & 7)) & 7;
    gload_lds16(Kb + (size_t)row * 1024 + ls * 8, sm + p * 2048 + w * 512);
  }
  stage_slice(0, 0);
  stage_slice(1, 1);
  const int qrow = n0 + w * 16 + r;
  const u16* Qp = Q + ((size_t)(b * 4096 + qrow)) * 1024 + h * 64 + g * 8;
  bf16x8 aq0 = *(const bf16x8*)Qp;
  bf16x8 aq1 = *(const bf16x8*)(Qp + 32);
  asm volatile("s_waitcnt vmcnt(4)" ::: "memory");
  __builtin_amdgcn_s_barrier();

  f32x4 dotv[16];
  __builtin_amdgcn_s_setprio(1);
#pragma unroll
  for (int kf = 0; kf < 16; ++kf) {
    int row = kf * 16 + r;
    bf16x8 kb0 = *(const bf16x8*)&sm[row * 64 + ((g + row) & 7) * 8];
    bf16x8 kb1 = *(const bf16x8*)&sm[row * 64 + ((4 + g + row) & 7) * 8];
    f32x4 d = f32x4{0.f, 0.f, 0.f, 0.f};
    d = mfma16(kb0, aq0, d);
    d = mfma16(kb1, aq1, d);
    dotv[kf] = d;
  }
  __builtin_amdgcn_s_setprio(0);
  asm volatile("s_waitcnt vmcnt(2)" ::: "memory");
  __builtin_amdgcn_s_barrier();

  float mx = -3.4e38f;
#pragma unroll
  for (int kf = 0; kf < 16; ++kf)
    mx = fmaxf(mx, fmaxf(fmaxf(dotv[kf][0], dotv[kf][1]), fmaxf(dotv[kf][2], dotv[kf][3])));
  mx = fmaxf(mx, __shfl_xor(mx, 16, 64));
  mx = fmaxf(mx, __shfl_xor(mx, 32, 64));
  float ssum = 0.f;
#pragma unroll
  for (int kf = 0; kf < 16; ++kf)
#pragma unroll
    for (int j = 0; j < 4; ++j) {
      float p = __builtin_amdgcn_exp2f(dotv[kf][j] - mx);
      dotv[kf][j] = p;
      ssum += p;
    }
  ssum += __shfl_xor(ssum, 16, 64);
  ssum += __shfl_xor(ssum, 32, 64);
  const float inv = 1.f / ssum;
  float invv[4];
#pragma unroll
  for (int rr = 0; rr < 4; ++rr) invv[rr] = __shfl(inv, 4 * g + rr, 64);

  const int q16 = w * 16 + r;
  const int qx = (q16 & 7) << 3;
#pragma unroll
  for (int kf = 0; kf < 16; ++kf) {
    uint2 val;
    val.x = pk2(dotv[kf][0], dotv[kf][1]);
    val.y = pk2(dotv[kf][2], dotv[kf][3]);
    *(uint2*)&sm[(q16 * 256 + kf * 16 + 4 * g) ^ qx] = val;
  }

  f32x4 oacc[4];
#pragma unroll
  for (int df = 0; df < 4; ++df) oacc[df] = f32x4{0.f, 0.f, 0.f, 0.f};
#pragma unroll
  for (int ph = 0; ph < 4; ++ph) {
    const u16* vb = vbase + (ph & 1) * 4096;
    __builtin_amdgcn_s_setprio(1);
#pragma unroll
    for (int kk2 = 0; kk2 < 2; ++kk2) {
      int kk = ph * 2 + kk2;
      bf16x8 ap = *(const bf16x8*)&sm[(q16 * 256 + kk * 32 + g * 8) ^ qx];
#pragma unroll
      for (int df = 0; df < 4; ++df) {
        int d = df * 16 + r;
        bf16x8 bv = *(const bf16x8*)&vb[d * 64 + ((kk2 * 4 + g) ^ (d & 7)) * 8];
        oacc[df] = mfma16(ap, bv, oacc[df]);
      }
    }
    __builtin_amdgcn_s_setprio(0);
    if (ph < 3) {
      asm volatile("s_waitcnt vmcnt(0)" ::: "memory");
      __builtin_amdgcn_s_barrier();
      if (ph < 2) stage_slice(ph + 2, ph & 1);
    }
  }

  u16* myO = sm + w * 4096;
#pragma unroll
  for (int df = 0; df < 4; ++df)
#pragma unroll
    for (int rr = 0; rr < 4; ++rr) {
      int row = 4 * g + rr;
      int col = df * 16 + r;
      myO[row * 64 + (((col >> 3) ^ (row & 7)) << 3) + (col & 7)] = f2bf(oacc[df][rr] * invv[rr]);
    }
#pragma unroll
  for (int i = 0; i < 2; ++i) {
    int idx = i * 64 + lane;
    int row = idx >> 3, c8 = idx & 7;
    bf16x8 v = *(const bf16x8*)&myO[row * 64 + ((c8 ^ (row & 7)) << 3)];
    *(bf16x8*)&Out[((size_t)(b * 4096 + n0 + w * 16 + row)) * 1024 + h * 64 + c8 * 8] = v;
  }
}

extern "C" void kernel_launch(void* const* d_in, const int* in_sizes, int n_in,
                              void* d_out, int out_size, void* d_ws, size_t ws_size,
                              hipStream_t stream) {
  const float* x  = (const float*)d_in[0];
  const float* Wq = (const float*)d_in[1];
  const float* Wk = (const float*)d_in[2];
  const float* Wv = (const float*)d_in[3];
  const float* pk = (const float*)d_in[4];
  const float* pv = (const float*)d_in[5];
  const float* Wo = (const float*)d_in[6];
  const float* bo = (const float*)d_in[7];

  u16* ws = (u16*)d_ws;
  u16* xbf   = ws;                   // [4][4096][1024]
  u16* xT    = xbf + 16777216;       // [4][1024][4096] == xT_flat [4096][4096]
  u16* wqb   = xT + 16777216;        // [1024][1024]
  u16* wkb   = wqb + 1048576;
  u16* wvb   = wkb + 1048576;
  u16* wob   = wvb + 1048576;
  u16* projT = wob + 1048576;        // [512][4096]
  u16* Qb    = projT + 2097152;      // [16384][1024]; holds xp bf16 partials first
  u16* xp    = Qb + 16777216;        // [512][4096] bf16
  u16* klow  = xp + 2097152;         // [4][256][1024]
  u16* vT    = klow + 1048576;       // [4][1024][256]
  u16* aout  = xbf;                  // reuse after Q GEMM
  u16* xp_part = Qb;                 // [4 z][512][4096] bf16 (in Qb region)

  // 1) x: convert + row-major bf16 + transpose (one read of x)
  cvt_xpose_kernel<<<dim3(16, 64, 4), 256, 0, stream>>>(x, xbf, xT, 4096, 1024,
                                                        4194304, 4194304, 4194304);
  // 2) weights + proj transposes merged
  cvt_misc_kernel<<<dim3(1024, 6), 256, 0, stream>>>(Wq, Wk, Wv, Wo, wqb, wkb, wvb, wob,
                                                     pk, pv, projT);
  // 3) xp partials (bf16): ONE GEMM M=512, N=4096, K=4096, split-K x4
  gemm_bt_kernel<4><<<dim3(32, 4, 4), 256, 0, stream>>>(
      projT, xT, nullptr, (void*)xp_part, nullptr, nullptr, 1.f,
      4096, 4096, 4096, 1024, 0, 0, 2097152, 1, 1024, 1024);
  // 4) reduce bf16 partials -> xp bf16 [512][4096]
  reduce4_kernel<<<1024, 256, 0, stream>>>(xp_part, xp);
  // 5) kv: z = b'*2 + half; K half -> klow row-major, V half -> vT transposed
  gemm_bt_kernel<3><<<dim3(8, 2, 8), 256, 0, stream>>>(
      xp, wkb, wvb, (void*)klow, vT, nullptr, 1.f,
      4096, 1024, 1024, 1024, 1048576, 0, 262144, 2, 1024, 0);
  // 6) Q = (x @ Wq^T) * QSCALE — BK=64 kernel (won the R17 A/B)
  qgemm64_kernel<0><<<dim3(8, 128), 256, 0, stream>>>(
      xbf, wqb, (void*)Qb, nullptr, QSCALE, 1024, 1024, 1024, 1024);
  // 7) attention
  attn_kernel<<<dim3(64, 16, 4), 256, 0, stream>>>(Qb, klow, vT, aout);
  // 8) final = attn_out @ Wo^T + bo -> fp32 d_out — BK=64 kernel
  qgemm64_kernel<1><<<dim3(8, 128), 256, 0, stream>>>(
      aout, wob, d_out, bo, 1.f, 1024, 1024, 1024, 1024);
}

// Round 20
// 200.053 us; speedup vs baseline: 1.0850x; 1.0081x over previous
//
#include <hip/hip_runtime.h>
#include <hip/hip_bf16.h>
#include <stdint.h>

typedef unsigned short u16;
typedef __attribute__((ext_vector_type(8))) short bf16x8;   // 8 bf16 = 4 VGPRs
typedef __attribute__((ext_vector_type(4))) float f32x4;

#define DEV __device__ __forceinline__

DEV u16 f2bf(float f) {
  union { float f; unsigned u; } v; v.f = f;
  unsigned r = (v.u + 0x7fffu + ((v.u >> 16) & 1u)) >> 16;   // RNE
  return (u16)r;
}

DEV float bf2f(u16 h) {
  union { unsigned u; float f; } v; v.u = ((unsigned)h) << 16;
  return v.f;
}

// packed 2x f32 -> 2x bf16 (v_cvt_pk_bf16_f32), RNE
DEV unsigned pk2(float lo, float hi) {
  union { __hip_bfloat162 h; unsigned u; } c;
  c.h = __float22bfloat162_rn(make_float2(lo, hi));
  return c.u;
}

DEV f32x4 mfma16(bf16x8 a, bf16x8 b, f32x4 c) {
  return __builtin_amdgcn_mfma_f32_16x16x32_bf16(a, b, c, 0, 0, 0);
}

DEV void gload_lds16(const u16* g, u16* l) {
  __builtin_amdgcn_global_load_lds((const __attribute__((address_space(1))) void*)g,
                                   (__attribute__((address_space(3))) void*)l, 16, 0, 0);
}

// softmax logit pre-scale folded into Q: dh^-0.5 (=1/8) * log2(e), so exp = exp2
#define QSCALE 0.18033688011112042f

// ---------------- fused fp32 -> bf16 convert (+ optional row-major copy) + transpose ----------------
__global__ void cvt_xpose_kernel(const float* __restrict__ src, u16* __restrict__ dst_rm,
                                 u16* __restrict__ dst_tp, int R, int C,
                                 long zS, long zRM, long zTP) {
  __shared__ u16 tile[64][72];
  src += (size_t)blockIdx.z * zS;
  dst_tp += (size_t)blockIdx.z * zTP;
  int r0 = blockIdx.y * 64, c0 = blockIdx.x * 64;
  int tr = threadIdx.x >> 2, tc = (threadIdx.x & 3) * 16;
  const float* s = src + (size_t)(r0 + tr) * C + c0 + tc;
  u16 loc[16];
#pragma unroll
  for (int q = 0; q < 4; ++q) {
    float4 v = ((const float4*)s)[q];
    loc[q * 4 + 0] = f2bf(v.x); loc[q * 4 + 1] = f2bf(v.y);
    loc[q * 4 + 2] = f2bf(v.z); loc[q * 4 + 3] = f2bf(v.w);
  }
#pragma unroll
  for (int i = 0; i < 16; ++i) tile[tr][tc + i] = loc[i];
  if (dst_rm) {
    u16* d = dst_rm + (size_t)blockIdx.z * zRM + (size_t)(r0 + tr) * C + c0 + tc;
    *(bf16x8*)d = *(const bf16x8*)&loc[0];
    *(bf16x8*)(d + 8) = *(const bf16x8*)&loc[8];
  }
  __syncthreads();
  u16 tmp[16];
#pragma unroll
  for (int i = 0; i < 16; ++i) tmp[i] = tile[tc + i][tr];
  u16* d = dst_tp + (size_t)(c0 + tr) * R + r0 + tc;
  *(bf16x8*)d = *(const bf16x8*)&tmp[0];
  *(bf16x8*)(d + 8) = *(const bf16x8*)&tmp[8];
}

// ---------------- merged: 4 weight converts (y 0-3) + proj_k/proj_v transposes (y 4-5) ----------------
__global__ void cvt_misc_kernel(const float* __restrict__ s0, const float* __restrict__ s1,
                                const float* __restrict__ s2, const float* __restrict__ s3,
                                u16* __restrict__ d0, u16* __restrict__ d1,
                                u16* __restrict__ d2, u16* __restrict__ d3,
                                const float* __restrict__ pk, const float* __restrict__ pv,
                                u16* __restrict__ projT) {
  __shared__ u16 tile[64][72];
  const int y = blockIdx.y;
  if (y < 4) {
    const float* s; u16* d;
    switch (y) {
      case 0: s = s0; d = d0; break;
      case 1: s = s1; d = d1; break;
      case 2: s = s2; d = d2; break;
      default: s = s3; d = d3; break;
    }
    int i = blockIdx.x * 256 + threadIdx.x;
    float4 v = ((const float4*)s)[i];
    ushort4 o; o.x = f2bf(v.x); o.y = f2bf(v.y); o.z = f2bf(v.z); o.w = f2bf(v.w);
    ((ushort4*)d)[i] = o;
    return;
  }
  if (blockIdx.x >= 256) return;
  const float* src = (y == 4) ? pk : pv;
  u16* dst = projT + (size_t)(y - 4) * 1048576;
  int r0 = (blockIdx.x >> 2) * 64, c0 = (blockIdx.x & 3) * 64;
  int tr = threadIdx.x >> 2, tc = (threadIdx.x & 3) * 16;
  const float* s = src + (size_t)(r0 + tr) * 256 + c0 + tc;
  u16 loc[16];
#pragma unroll
  for (int q = 0; q < 4; ++q) {
    float4 v = ((const float4*)s)[q];
    loc[q * 4 + 0] = f2bf(v.x); loc[q * 4 + 1] = f2bf(v.y);
    loc[q * 4 + 2] = f2bf(v.z); loc[q * 4 + 3] = f2bf(v.w);
  }
#pragma unroll
  for (int i = 0; i < 16; ++i) tile[tr][tc + i] = loc[i];
  __syncthreads();
  u16 tmp[16];
#pragma unroll
  for (int i = 0; i < 16; ++i) tmp[i] = tile[tc + i][tr];
  u16* d = dst + (size_t)(c0 + tr) * 4096 + r0 + tc;
  *(bf16x8*)d = *(const bf16x8*)&tmp[0];
  *(bf16x8*)(d + 8) = *(const bf16x8*)&tmp[8];
}

// ---------------- split-K reduce: 4x bf16 partials -> bf16, fp32 accum ----------------
__global__ void reduce4_kernel(const u16* __restrict__ part, u16* __restrict__ out) {
  int i = blockIdx.x * 256 + threadIdx.x;   // bf16x8 unit; total 262144 units
  bf16x8 a = ((const bf16x8*)part)[i];
  bf16x8 b = ((const bf16x8*)part)[i + 262144];
  bf16x8 c = ((const bf16x8*)part)[i + 524288];
  bf16x8 d = ((const bf16x8*)part)[i + 786432];
  u16 o[8];
#pragma unroll
  for (int j = 0; j < 8; ++j)
    o[j] = f2bf(bf2f((u16)a[j]) + bf2f((u16)b[j]) + bf2f((u16)c[j]) + bf2f((u16)d[j]));
  ((bf16x8*)out)[i] = *(const bf16x8*)&o[0];
}

// ------------- 128x128 2-phase GEMM (xp split-K only, bf16 partial epilogue) -------------
__global__ __launch_bounds__(256, 4)
void gemm_bt_kernel(const u16* __restrict__ A, const u16* __restrict__ Bt,
                    void* __restrict__ Cout, int ldA, int ldB, int ldC, int Klen,
                    long zC, long kChunkA, long kChunkB) {
  __shared__ __align__(16) u16 smA[2][128 * 32];
  __shared__ __align__(16) u16 smB[2][128 * 32];
  const int t = threadIdx.x;
  const int lane = t & 63, wave = t >> 6;
  const int wm = wave & 1, wn = wave >> 1;
  const int g = lane >> 4, r = lane & 15;
  const int id = blockIdx.y * gridDim.x + blockIdx.x;
  const int cpx = (gridDim.x * gridDim.y) >> 3;
  const int s = (id & 7) * cpx + (id >> 3);
  const int bx = s % gridDim.x, by = s / gridDim.x;
  const int z = blockIdx.z;
  const u16* Ab = A + (size_t)z * kChunkA;
  const u16* Bb = Bt + (size_t)z * kChunkB;
  const int m0 = by * 128, n0 = bx * 128;
  const int srow = t >> 2;
  const int lslot = ((t & 3) + 4 - ((srow >> 1) & 3)) & 3;

  f32x4 acc[4][4];
#pragma unroll
  for (int m = 0; m < 4; ++m)
#pragma unroll
    for (int n = 0; n < 4; ++n) acc[m][n] = f32x4{0.f, 0.f, 0.f, 0.f};

  auto STAGE = [&](int buf, int k0) {
#pragma unroll
    for (int p = 0; p < 2; ++p) {
      int row = p * 64 + srow;
      gload_lds16(Ab + (size_t)(m0 + row) * ldA + k0 + lslot * 8, &smA[buf][p * 2048 + wave * 512]);
      gload_lds16(Bb + (size_t)(n0 + row) * ldB + k0 + lslot * 8, &smB[buf][p * 2048 + wave * 512]);
    }
  };

  const int nt = Klen >> 5;
  STAGE(0, 0);
  __syncthreads();
  int cur = 0;
  for (int it = 0; it < nt; ++it) {
    if (it + 1 < nt) STAGE(cur ^ 1, (it + 1) << 5);
    bf16x8 af[4], bfr[4];
#pragma unroll
    for (int m = 0; m < 4; ++m) {
      int row = wm * 64 + m * 16 + r;
      int ps = (g + (row >> 1)) & 3;
      af[m] = *(const bf16x8*)&smA[cur][row * 32 + ps * 8];
    }
#pragma unroll
    for (int n = 0; n < 4; ++n) {
      int row = wn * 64 + n * 16 + r;
      int ps = (g + (row >> 1)) & 3;
      bfr[n] = *(const bf16x8*)&smB[cur][row * 32 + ps * 8];
    }
#pragma unroll
    for (int m = 0; m < 4; ++m)
#pragma unroll
      for (int n = 0; n < 4; ++n)
        acc[m][n] = mfma16(af[m], bfr[n], acc[m][n]);
    __syncthreads();
    cur ^= 1;
  }

  // bf16 raw partial at z*zC, LDS-staged coalesced stores
  u16* myT = (u16*)&smA[0][0] + wave * 4096;
  u16* Cg = (u16*)Cout + (size_t)z * zC + (size_t)(m0 + wm * 64) * ldC + n0 + wn * 64;
#pragma unroll
  for (int m = 0; m < 4; ++m)
#pragma unroll
    for (int n = 0; n < 4; ++n)
#pragma unroll
      for (int rr = 0; rr < 4; ++rr) {
        int rl = m * 16 + 4 * g + rr;
        int cl = n * 16 + r;
        myT[rl * 64 + (((cl >> 3) ^ (rl & 7)) << 3) + (cl & 7)] = f2bf(acc[m][n][rr]);
      }
#pragma unroll
  for (int i = 0; i < 8; ++i) {
    int idx = i * 64 + lane;
    int row = idx >> 3, c8 = idx & 7;
    bf16x8 v = *(const bf16x8*)&myT[row * 64 + ((c8 ^ (row & 7)) << 3)];
    *(bf16x8*)&Cg[(size_t)row * ldC + c8 * 8] = v;
  }
}

// ------------- FUSED: kv GEMM (128 blocks, by<16) + Q GEMM BK=64 (1024 blocks, by>=16) -------------
__global__ __launch_bounds__(256, 2)
void qkv_fused_kernel(const u16* __restrict__ A, const u16* __restrict__ Wq,
                      u16* __restrict__ Qout, float cscale,
                      const u16* __restrict__ xp, const u16* __restrict__ wk,
                      const u16* __restrict__ wv, u16* __restrict__ klow,
                      u16* __restrict__ vT) {
  __shared__ __align__(16) u16 lds[32768];   // 64 KB
  const int t = threadIdx.x;
  const int lane = t & 63, wave = t >> 6;
  const int g = lane >> 4, r = lane & 15;

  if (blockIdx.y < 16) {
    // ---- kv path: idx in [0,128) ----
    const int idx = blockIdx.y * 8 + blockIdx.x;
    const int z = idx >> 4, id2 = idx & 15;
    const int s2 = (id2 & 7) * 2 + (id2 >> 3);     // original grid (8,2): cpx=2
    const int bx2 = s2 & 7, by2 = s2 >> 3;
    const int bb = z & 1, kc = z >> 1;
    const u16* Ab = xp + (size_t)bb * 1048576 + (size_t)kc * 1024;  // ldA 4096
    const u16* Bb = bb ? wv : wk;                                    // ldB 1024
    const int m0 = by2 * 128, n0 = bx2 * 128;
    const int wm = wave & 1, wn = wave >> 1;
    const int srow = t >> 2;
    const int lslot = ((t & 3) + 4 - ((srow >> 1) & 3)) & 3;

    f32x4 acc[4][4];
#pragma unroll
    for (int m = 0; m < 4; ++m)
#pragma unroll
      for (int n = 0; n < 4; ++n) acc[m][n] = f32x4{0.f, 0.f, 0.f, 0.f};

    auto STAGE = [&](int buf, int k0) {
#pragma unroll
      for (int p = 0; p < 2; ++p) {
        int row = p * 64 + srow;
        gload_lds16(Ab + (size_t)(m0 + row) * 4096 + k0 + lslot * 8,
                    lds + buf * 4096 + p * 2048 + wave * 512);
        gload_lds16(Bb + (size_t)(n0 + row) * 1024 + k0 + lslot * 8,
                    lds + 8192 + buf * 4096 + p * 2048 + wave * 512);
      }
    };

    STAGE(0, 0);
    __syncthreads();
    int cur = 0;
    for (int it = 0; it < 32; ++it) {
      if (it + 1 < 32) STAGE(cur ^ 1, (it + 1) << 5);
      const u16* sA = lds + cur * 4096;
      const u16* sB = lds + 8192 + cur * 4096;
      bf16x8 af[4], bfr[4];
#pragma unroll
      for (int m = 0; m < 4; ++m) {
        int row = wm * 64 + m * 16 + r;
        int ps = (g + (row >> 1)) & 3;
        af[m] = *(const bf16x8*)&sA[row * 32 + ps * 8];
      }
#pragma unroll
      for (int n = 0; n < 4; ++n) {
        int row = wn * 64 + n * 16 + r;
        int ps = (g + (row >> 1)) & 3;
        bfr[n] = *(const bf16x8*)&sB[row * 32 + ps * 8];
      }
#pragma unroll
      for (int m = 0; m < 4; ++m)
#pragma unroll
        for (int n = 0; n < 4; ++n)
          acc[m][n] = mfma16(af[m], bfr[n], acc[m][n]);
      __syncthreads();
      cur ^= 1;
    }

    if (bb == 0) {          // K half: row-major bf16 into klow[kc]
      u16* C = klow + (size_t)kc * 262144;
#pragma unroll
      for (int n = 0; n < 4; ++n) {
        int col = n0 + wn * 64 + n * 16 + r;
#pragma unroll
        for (int m = 0; m < 4; ++m) {
          int rowb = m0 + wm * 64 + m * 16 + 4 * g;
#pragma unroll
          for (int rr = 0; rr < 4; ++rr)
            C[(size_t)(rowb + rr) * 1024 + col] = f2bf(acc[m][n][rr]);
        }
      }
    } else {                // V half: transposed bf16 into vT[kc] (ld 256)
      u16* C = vT + (size_t)kc * 262144;
#pragma unroll
      for (int n = 0; n < 4; ++n) {
        int col = n0 + wn * 64 + n * 16 + r;
#pragma unroll
        for (int m = 0; m < 4; ++m) {
          int rowb = m0 + wm * 64 + m * 16 + 4 * g;
          ushort4 o;
          o.x = f2bf(acc[m][n][0]); o.y = f2bf(acc[m][n][1]);
          o.z = f2bf(acc[m][n][2]); o.w = f2bf(acc[m][n][3]);
          *(ushort4*)&C[(size_t)col * 256 + rowb] = o;
        }
      }
    }
    return;
  }

  // ---- Q path: qgemm64 OMODE0, id space identical to standalone grid (8,128) ----
  const int wm = wave >> 1, wn = wave & 1;           // 2M x 2N
  const int id = (blockIdx.y - 16) * 8 + blockIdx.x; // 0..1023
  const int s = (id & 7) * 128 + (id >> 3);          // cpx = 1024>>3 = 128
  const int bx = s & 7, by = s >> 3;
  const int m0 = by * 128, n0 = bx * 128;

  auto STAGE = [&](int buf, int k0) {
#pragma unroll
    for (int j = 0; j < 4; ++j) {
      int u = j * 256 + t;
      int row = u >> 3, psl = u & 7;
      int sl = (psl + 8 - (row & 7)) & 7;
      gload_lds16(A + (size_t)(m0 + row) * 1024 + k0 + sl * 8,
                  lds + buf * 16384 + u * 8);
    }
#pragma unroll
    for (int j = 0; j < 4; ++j) {
      int u = j * 256 + t;
      int row = u >> 3, psl = u & 7;
      int sl = (psl + 8 - (row & 7)) & 7;
      gload_lds16(Wq + (size_t)(n0 + row) * 1024 + k0 + sl * 8,
                  lds + buf * 16384 + 8192 + u * 8);
    }
  };

  f32x4 acc[4][4];
#pragma unroll
  for (int m = 0; m < 4; ++m)
#pragma unroll
    for (int n = 0; n < 4; ++n) acc[m][n] = f32x4{0.f, 0.f, 0.f, 0.f};

  STAGE(0, 0);
  asm volatile("s_waitcnt vmcnt(0)" ::: "memory");
  __builtin_amdgcn_s_barrier();

  int cur = 0;
  for (int it = 0; it < 16; ++it) {
    if (it + 1 < 16) STAGE(cur ^ 1, (it + 1) << 6);
    const u16* Ab = lds + cur * 16384;
    const u16* Bb = Ab + 8192;
    bf16x8 af[4][2], bfr[4][2];
#pragma unroll
    for (int m = 0; m < 4; ++m) {
      int row = wm * 64 + m * 16 + r;
      af[m][0] = *(const bf16x8*)&Ab[row * 64 + (((g + row) & 7) << 3)];
      af[m][1] = *(const bf16x8*)&Ab[row * 64 + (((4 + g + row) & 7) << 3)];
    }
#pragma unroll
    for (int n = 0; n < 4; ++n) {
      int row = wn * 64 + n * 16 + r;
      bfr[n][0] = *(const bf16x8*)&Bb[row * 64 + (((g + row) & 7) << 3)];
      bfr[n][1] = *(const bf16x8*)&Bb[row * 64 + (((4 + g + row) & 7) << 3)];
    }
#pragma unroll
    for (int m = 0; m < 4; ++m)
#pragma unroll
      for (int n = 0; n < 4; ++n) {
        acc[m][n] = mfma16(af[m][0], bfr[n][0], acc[m][n]);
        acc[m][n] = mfma16(af[m][1], bfr[n][1], acc[m][n]);
      }
    if (it + 1 < 16) {
      asm volatile("s_waitcnt vmcnt(0)" ::: "memory");
      __builtin_amdgcn_s_barrier();
    }
    cur ^= 1;
  }
  __builtin_amdgcn_s_barrier();

  u16* myT = lds + wave * 4096;
  u16* Cg = Qout + (size_t)(m0 + wm * 64) * 1024 + n0 + wn * 64;
#pragma unroll
  for (int m = 0; m < 4; ++m)
#pragma unroll
    for (int n = 0; n < 4; ++n)
#pragma unroll
      for (int rr = 0; rr < 4; ++rr) {
        int rl = m * 16 + 4 * g + rr;
        int cl = n * 16 + r;
        myT[rl * 64 + (((cl >> 3) ^ (rl & 7)) << 3) + (cl & 7)] = f2bf(acc[m][n][rr] * cscale);
      }
#pragma unroll
  for (int i = 0; i < 8; ++i) {
    int idx = i * 64 + lane;
    int row = idx >> 3, c8 = idx & 7;
    bf16x8 v = *(const bf16x8*)&myT[row * 64 + ((c8 ^ (row & 7)) << 3)];
    *(bf16x8*)&Cg[(size_t)row * 1024 + c8 * 8] = v;
  }
}

// ------------- 128x128 BK=64 GEMM (final GEMM, fp32+bias) -------------
__global__ __launch_bounds__(256, 2)
void qgemm64_kernel(const u16* __restrict__ A, const u16* __restrict__ Bt,
                    float* __restrict__ Cout, const float* __restrict__ bias,
                    int ldA, int ldB, int ldC, int Klen) {
  __shared__ __align__(16) u16 lds[32768];   // 64 KB
  const int t = threadIdx.x;
  const int lane = t & 63, wave = t >> 6;
  const int g = lane >> 4, r = lane & 15;
  const int wm = wave >> 1, wn = wave & 1;
  const int id = blockIdx.y * gridDim.x + blockIdx.x;
  const int cpx = (gridDim.x * gridDim.y) >> 3;
  const int s = (id & 7) * cpx + (id >> 3);
  const int bx = s & 7, by = s >> 3;
  const int m0 = by * 128, n0 = bx * 128;

  auto STAGE = [&](int buf, int k0) {
#pragma unroll
    for (int j = 0; j < 4; ++j) {
      int u = j * 256 + t;
      int row = u >> 3, psl = u & 7;
      int sl = (psl + 8 - (row & 7)) & 7;
      gload_lds16(A + (size_t)(m0 + row) * ldA + k0 + sl * 8,
                  lds + buf * 16384 + u * 8);
    }
#pragma unroll
    for (int j = 0; j < 4; ++j) {
      int u = j * 256 + t;
      int row = u >> 3, psl = u & 7;
      int sl = (psl + 8 - (row & 7)) & 7;
      gload_lds16(Bt + (size_t)(n0 + row) * ldB + k0 + sl * 8,
                  lds + buf * 16384 + 8192 + u * 8);
    }
  };

  f32x4 acc[4][4];
#pragma unroll
  for (int m = 0; m < 4; ++m)
#pragma unroll
    for (int n = 0; n < 4; ++n) acc[m][n] = f32x4{0.f, 0.f, 0.f, 0.f};

  const int nt = Klen >> 6;   // 16
  STAGE(0, 0);
  asm volatile("s_waitcnt vmcnt(0)" ::: "memory");
  __builtin_amdgcn_s_barrier();

  int cur = 0;
  for (int it = 0; it < nt; ++it) {
    if (it + 1 < nt) STAGE(cur ^ 1, (it + 1) << 6);
    const u16* Ab = lds + cur * 16384;
    const u16* Bb = Ab + 8192;
    bf16x8 af[4][2], bfr[4][2];
#pragma unroll
    for (int m = 0; m < 4; ++m) {
      int row = wm * 64 + m * 16 + r;
      af[m][0] = *(const bf16x8*)&Ab[row * 64 + (((g + row) & 7) << 3)];
      af[m][1] = *(const bf16x8*)&Ab[row * 64 + (((4 + g + row) & 7) << 3)];
    }
#pragma unroll
    for (int n = 0; n < 4; ++n) {
      int row = wn * 64 + n * 16 + r;
      bfr[n][0] = *(const bf16x8*)&Bb[row * 64 + (((g + row) & 7) << 3)];
      bfr[n][1] = *(const bf16x8*)&Bb[row * 64 + (((4 + g + row) & 7) << 3)];
    }
#pragma unroll
    for (int m = 0; m < 4; ++m)
#pragma unroll
      for (int n = 0; n < 4; ++n) {
        acc[m][n] = mfma16(af[m][0], bfr[n][0], acc[m][n]);
        acc[m][n] = mfma16(af[m][1], bfr[n][1], acc[m][n]);
      }
    if (it + 1 < nt) {
      asm volatile("s_waitcnt vmcnt(0)" ::: "memory");
      __builtin_amdgcn_s_barrier();
    }
    cur ^= 1;
  }
  __builtin_amdgcn_s_barrier();

  float* myF = (float*)lds + wave * 2048;
  float bvn[4];
#pragma unroll
  for (int n = 0; n < 4; ++n) bvn[n] = bias[n0 + wn * 64 + n * 16 + r];
  float* Cg = Cout + (size_t)(m0 + wm * 64) * ldC + n0 + wn * 64;
#pragma unroll
  for (int np = 0; np < 2; ++np) {
#pragma unroll
    for (int n2 = 0; n2 < 2; ++n2)
#pragma unroll
      for (int m = 0; m < 4; ++m)
#pragma unroll
        for (int rr = 0; rr < 4; ++rr) {
          int rl = m * 16 + 4 * g + rr;
          int cl = n2 * 16 + r;
          myF[rl * 32 + ((((cl >> 2) ^ (rl & 7)) & 7) << 2) + (cl & 3)] =
              acc[m][np * 2 + n2][rr] + bvn[np * 2 + n2];
        }
#pragma unroll
    for (int i = 0; i < 8; ++i) {
      int idx = i * 64 + lane;
      int row = idx >> 3, c = idx & 7;
      float4 v = *(const float4*)&myF[row * 32 + (((c ^ (row & 7)) & 7) << 2)];
      *(float4*)&Cg[(size_t)row * ldC + np * 32 + c * 4] = v;
    }
  }
}

// ------------- fused attention (frozen from R14) -------------
__global__ __launch_bounds__(256, 3)
void attn_kernel(const u16* __restrict__ Q, const u16* __restrict__ Kl,
                 const u16* __restrict__ VT, u16* __restrict__ Out) {
  __shared__ __align__(16) u16 sm[24576];   // 48 KB
  const int t = threadIdx.x, lane = t & 63, w = t >> 6;
  const int g = lane >> 4, r = lane & 15;
  const int id = (blockIdx.y << 6) | blockIdx.x;
  const int s = (id & 7) * (gridDim.y << 3) + (id >> 3);
  const int b = blockIdx.z, h = s >> 6, n0 = (s & 63) * 64;
  const u16* Kb = Kl + (size_t)b * 262144 + h * 64;
  const u16* Vb = VT + (size_t)b * 262144 + (size_t)(h * 64) * 256;
  u16* vbase = sm + 16384;

  auto stage_slice = [&](int sl64, int buf) {
#pragma unroll
    for (int i = 0; i < 2; ++i) {
      int u = i * 256 + t;
      int d = u >> 3, ps = u & 7;
      gload_lds16(Vb + (size_t)d * 256 + sl64 * 64 + (ps ^ (d & 7)) * 8,
                  vbase + buf * 4096 + i * 2048 + t * 8);
    }
  };

#pragma unroll
  for (int p = 0; p < 8; ++p) {
    int row = p * 32 + (t >> 3);
    int ls = ((t & 7) + 8 - (row & 7)) & 7;
    gload_lds16(Kb + (size_t)row * 1024 + ls * 8, sm + p * 2048 + w * 512);
  }
  stage_slice(0, 0);
  stage_slice(1, 1);
  const int qrow = n0 + w * 16 + r;
  const u16* Qp = Q + ((size_t)(b * 4096 + qrow)) * 1024 + h * 64 + g * 8;
  bf16x8 aq0 = *(const bf16x8*)Qp;
  bf16x8 aq1 = *(const bf16x8*)(Qp + 32);
  asm volatile("s_waitcnt vmcnt(4)" ::: "memory");
  __builtin_amdgcn_s_barrier();

  f32x4 dotv[16];
  __builtin_amdgcn_s_setprio(1);
#pragma unroll
  for (int kf = 0; kf < 16; ++kf) {
    int row = kf * 16 + r;
    bf16x8 kb0 = *(const bf16x8*)&sm[row * 64 + ((g + row) & 7) * 8];
    bf16x8 kb1 = *(const bf16x8*)&sm[row * 64 + ((4 + g + row) & 7) * 8];
    f32x4 d = f32x4{0.f, 0.f, 0.f, 0.f};
    d = mfma16(kb0, aq0, d);
    d = mfma16(kb1, aq1, d);
    dotv[kf] = d;
  }
  __builtin_amdgcn_s_setprio(0);
  asm volatile("s_waitcnt vmcnt(2)" ::: "memory");
  __builtin_amdgcn_s_barrier();

  float mx = -3.4e38f;
#pragma unroll
  for (int kf = 0; kf < 16; ++kf)
    mx = fmaxf(mx, fmaxf(fmaxf(dotv[kf][0], dotv[kf][1]), fmaxf(dotv[kf][2], dotv[kf][3])));
  mx = fmaxf(mx, __shfl_xor(mx, 16, 64));
  mx = fmaxf(mx, __shfl_xor(mx, 32, 64));
  float ssum = 0.f;
#pragma unroll
  for (int kf = 0; kf < 16; ++kf)
#pragma unroll
    for (int j = 0; j < 4; ++j) {
      float p = __builtin_amdgcn_exp2f(dotv[kf][j] - mx);
      dotv[kf][j] = p;
      ssum += p;
    }
  ssum += __shfl_xor(ssum, 16, 64);
  ssum += __shfl_xor(ssum, 32, 64);
  const float inv = 1.f / ssum;
  float invv[4];
#pragma unroll
  for (int rr = 0; rr < 4; ++rr) invv[rr] = __shfl(inv, 4 * g + rr, 64);

  const int q16 = w * 16 + r;
  const int qx = (q16 & 7) << 3;
#pragma unroll
  for (int kf = 0; kf < 16; ++kf) {
    uint2 val;
    val.x = pk2(dotv[kf][0], dotv[kf][1]);
    val.y = pk2(dotv[kf][2], dotv[kf][3]);
    *(uint2*)&sm[(q16 * 256 + kf * 16 + 4 * g) ^ qx] = val;
  }

  f32x4 oacc[4];
#pragma unroll
  for (int df = 0; df < 4; ++df) oacc[df] = f32x4{0.f, 0.f, 0.f, 0.f};
#pragma unroll
  for (int ph = 0; ph < 4; ++ph) {
    const u16* vb = vbase + (ph & 1) * 4096;
    __builtin_amdgcn_s_setprio(1);
#pragma unroll
    for (int kk2 = 0; kk2 < 2; ++kk2) {
      int kk = ph * 2 + kk2;
      bf16x8 ap = *(const bf16x8*)&sm[(q16 * 256 + kk * 32 + g * 8) ^ qx];
#pragma unroll
      for (int df = 0; df < 4; ++df) {
        int d = df * 16 + r;
        bf16x8 bv = *(const bf16x8*)&vb[d * 64 + ((kk2 * 4 + g) ^ (d & 7)) * 8];
        oacc[df] = mfma16(ap, bv, oacc[df]);
      }
    }
    __builtin_amdgcn_s_setprio(0);
    if (ph < 3) {
      asm volatile("s_waitcnt vmcnt(0)" ::: "memory");
      __builtin_amdgcn_s_barrier();
      if (ph < 2) stage_slice(ph + 2, ph & 1);
    }
  }

  u16* myO = sm + w * 4096;
#pragma unroll
  for (int df = 0; df < 4; ++df)
#pragma unroll
    for (int rr = 0; rr < 4; ++rr) {
      int row = 4 * g + rr;
      int col = df * 16 + r;
      myO[row * 64 + (((col >> 3) ^ (row & 7)) << 3) + (col & 7)] = f2bf(oacc[df][rr] * invv[rr]);
    }
#pragma unroll
  for (int i = 0; i < 2; ++i) {
    int idx = i * 64 + lane;
    int row = idx >> 3, c8 = idx & 7;
    bf16x8 v = *(const bf16x8*)&myO[row * 64 + ((c8 ^ (row & 7)) << 3)];
    *(bf16x8*)&Out[((size_t)(b * 4096 + n0 + w * 16 + row)) * 1024 + h * 64 + c8 * 8] = v;
  }
}

extern "C" void kernel_launch(void* const* d_in, const int* in_sizes, int n_in,
                              void* d_out, int out_size, void* d_ws, size_t ws_size,
                              hipStream_t stream) {
  const float* x  = (const float*)d_in[0];
  const float* Wq = (const float*)d_in[1];
  const float* Wk = (const float*)d_in[2];
  const float* Wv = (const float*)d_in[3];
  const float* pk = (const float*)d_in[4];
  const float* pv = (const float*)d_in[5];
  const float* Wo = (const float*)d_in[6];
  const float* bo = (const float*)d_in[7];

  u16* ws = (u16*)d_ws;
  u16* xbf   = ws;                   // [4][4096][1024]
  u16* xT    = xbf + 16777216;       // [4][1024][4096] == xT_flat [4096][4096]
  u16* wqb   = xT + 16777216;        // [1024][1024]
  u16* wkb   = wqb + 1048576;
  u16* wvb   = wkb + 1048576;
  u16* wob   = wvb + 1048576;
  u16* projT = wob + 1048576;        // [512][4096]
  u16* Qb    = projT + 2097152;      // [16384][1024]; holds xp bf16 partials first
  u16* xp    = Qb + 16777216;        // [512][4096] bf16
  u16* klow  = xp + 2097152;         // [4][256][1024]
  u16* vT    = klow + 1048576;       // [4][1024][256]
  u16* aout  = xbf;                  // reuse after Q GEMM
  u16* xp_part = Qb;                 // [4 z][512][4096] bf16 (in Qb region)

  // 1) x: convert + row-major bf16 + transpose (one read of x)
  cvt_xpose_kernel<<<dim3(16, 64, 4), 256, 0, stream>>>(x, xbf, xT, 4096, 1024,
                                                        4194304, 4194304, 4194304);
  // 2) weights + proj transposes merged
  cvt_misc_kernel<<<dim3(1024, 6), 256, 0, stream>>>(Wq, Wk, Wv, Wo, wqb, wkb, wvb, wob,
                                                     pk, pv, projT);
  // 3) xp partials (bf16): ONE GEMM M=512, N=4096, K=4096, split-K x4 (z = k-chunk)
  gemm_bt_kernel<<<dim3(32, 4, 4), 256, 0, stream>>>(
      projT, xT, (void*)xp_part, 4096, 4096, 4096, 1024, 2097152, 1024, 1024);
  // 4) reduce bf16 partials -> xp bf16 [512][4096]
  reduce4_kernel<<<1024, 256, 0, stream>>>(xp_part, xp);
  // 5) FUSED: kv (128 blocks, dispatched first) + Q = (x @ Wq^T)*QSCALE (1024 blocks)
  qkv_fused_kernel<<<dim3(8, 144), 256, 0, stream>>>(
      xbf, wqb, Qb, QSCALE, xp, wkb, wvb, klow, vT);
  // 6) attention
  attn_kernel<<<dim3(64, 16, 4), 256, 0, stream>>>(Qb, klow, vT, aout);
  // 7) final = attn_out @ Wo^T + bo -> fp32 d_out
  qgemm64_kernel<<<dim3(8, 128), 256, 0, stream>>>(
      aout, wob, (float*)d_out, bo, 1024, 1024, 1024, 1024);
}